// Round 1
// baseline (189.002 us; speedup 1.0000x reference)
//
#include <hip/hip_runtime.h>

typedef __attribute__((ext_vector_type(8))) short short8;
typedef __attribute__((ext_vector_type(4))) float f32x4;

__device__ inline float lrelu(float v){ return v > 0.f ? v : 0.01f*v; }
__device__ inline ushort f2bf(float f){
    unsigned u = __float_as_uint(f);
    return (ushort)((u + 0x7fffu + ((u >> 16) & 1u)) >> 16);
}
__device__ inline float bf2f(ushort h){ return __uint_as_float(((unsigned)h) << 16); }

#define M_ROWS 2048

// ---------------- prep: T[slot][card][512] = emb[card] @ Wslice ----------------
// slots: 0,1 = hW1 rows 0-63,64-127 ; 2,3,4 = bW1 rows 0-63,64-127,128-191
__global__ __launch_bounds__(512) void prep_T(const float* __restrict__ emb,
                                              const float* __restrict__ hW1,
                                              const float* __restrict__ bW1,
                                              float* __restrict__ T) {
    int b = blockIdx.x;          // slot*53 + card, 265 blocks
    int slot = b / 53, card = b % 53;
    const float* W = (slot < 2) ? (hW1 + slot * 64 * 512) : (bW1 + (slot - 2) * 64 * 512);
    int j = threadIdx.x;
    const float* e = emb + card * 64;
    float acc = 0.f;
    #pragma unroll 8
    for (int k = 0; k < 64; ++k) acc += e[k] * W[k * 512 + j];
    T[(size_t)b * 512 + j] = acc;
}

// ---------------- prep: transpose+convert weights to bf16 (N x K), zero-pad rows ----
__global__ void transpose_bf16(const float* __restrict__ in, ushort* __restrict__ out,
                               int K, int Nin, int Nout) {
    size_t idx = (size_t)blockIdx.x * 256 + threadIdx.x;
    if (idx >= (size_t)Nout * K) return;
    int n = (int)(idx / K), k = (int)(idx % K);
    float v = (n < Nin) ? in[(size_t)k * Nin + n] : 0.f;
    out[idx] = f2bf(v);
}

// ---------------- prep: Wct[512][2048] = transposed block-sum of oW1 ----------------
__global__ __launch_bounds__(256) void prep_Wct(const float* __restrict__ oW1,
                                                ushort* __restrict__ Wct) {
    __shared__ float tile[64][65];
    int kb = blockIdx.x;  // 0..31 over 2048 (X columns)
    int nb = blockIdx.y;  // 0..7  over 512  (R1 columns)
    int tid = threadIdx.x;
    int nl = tid & 63;
    for (int kl = tid >> 6; kl < 64; kl += 4) {
        int col = kb * 64 + kl;         // 0..2047
        int p = col >> 7, r = col & 127;
        int n = nb * 64 + nl;
        float s = 0.f;
        if (p < 6) {
            #pragma unroll
            for (int j = 0; j < 10; ++j) s += oW1[(size_t)((p * 10 + j) * 256 + r) * 512 + n];
        } else {
            int t = p - 6;
            #pragma unroll
            for (int i = 0; i < 6; ++i) s += oW1[(size_t)((i * 10 + t) * 256 + 128 + r) * 512 + n];
        }
        tile[kl][nl] = s;
    }
    __syncthreads();
    for (int nl2 = tid >> 6; nl2 < 64; nl2 += 4) {
        int kl2 = tid & 63;
        Wct[(size_t)(nb * 64 + nl2) * 2048 + kb * 64 + kl2] = f2bf(tile[kl2][nl2]);
    }
}

// ---------------- cards: parse, sort hero(4)/board(5) by (rank,suit), card id ----
__global__ void cards_kernel(const int* __restrict__ x, int* __restrict__ cid, int M) {
    int m = blockIdx.x * blockDim.x + threadIdx.x;
    if (m >= M) return;
    int kh[4], kb[5];
    #pragma unroll
    for (int i = 0; i < 4; ++i) { int r = x[m*18 + 2*i], s = x[m*18 + 2*i + 1]; kh[i] = r*8 + s; }
    #pragma unroll
    for (int i = 0; i < 5; ++i) { int r = x[m*18 + 8 + 2*i], s = x[m*18 + 9 + 2*i]; kb[i] = r*8 + s; }
    #pragma unroll
    for (int i = 1; i < 4; ++i) { int v = kh[i], j = i-1; while (j >= 0 && kh[j] > v) { kh[j+1]=kh[j]; --j; } kh[j+1]=v; }
    #pragma unroll
    for (int i = 1; i < 5; ++i) { int v = kb[i], j = i-1; while (j >= 0 && kb[j] > v) { kb[j+1]=kb[j]; --j; } kb[j+1]=v; }
    #pragma unroll
    for (int i = 0; i < 4; ++i) { int r = kh[i] >> 3, s = kh[i] & 7; cid[m*9 + i] = (r - 1) * s; }
    #pragma unroll
    for (int i = 0; i < 5; ++i) { int r = kb[i] >> 3, s = kb[i] & 7; cid[m*9 + 4 + i] = (r - 1) * s; }
}

// ---------------- layer-1 activations via gathered adds ----------------
__global__ __launch_bounds__(512) void build_Ah(const int* __restrict__ cid,
                                                const float* __restrict__ T,
                                                const float* __restrict__ hb1,
                                                ushort* __restrict__ Ah) {
    const int HP0[6] = {0,0,0,1,1,2}, HP1[6] = {1,2,3,2,3,3};
    int row = blockIdx.x;            // m*6 + p
    int m = row / 6, p = row % 6;
    int a = cid[m*9 + HP0[p]], b = cid[m*9 + HP1[p]];
    int j = threadIdx.x;
    float v = T[(size_t)(0*53 + a)*512 + j] + T[(size_t)(1*53 + b)*512 + j] + hb1[j];
    Ah[(size_t)row * 512 + j] = f2bf(lrelu(v));
}

__global__ __launch_bounds__(512) void build_Ab(const int* __restrict__ cid,
                                                const float* __restrict__ T,
                                                const float* __restrict__ bb1,
                                                ushort* __restrict__ Ab) {
    const int BT0[10] = {4,4,4,4,4,4,5,5,5,6};
    const int BT1[10] = {5,5,5,6,6,7,6,6,7,7};
    const int BT2[10] = {6,7,8,7,8,8,7,8,8,8};
    int row = blockIdx.x;            // m*10 + t
    int m = row / 10, t = row % 10;
    int c1 = cid[m*9 + BT0[t]], c2 = cid[m*9 + BT1[t]], c3 = cid[m*9 + BT2[t]];
    int j = threadIdx.x;
    float v = T[(size_t)(2*53 + c1)*512 + j] + T[(size_t)(3*53 + c2)*512 + j]
            + T[(size_t)(4*53 + c3)*512 + j] + bb1[j];
    Ab[(size_t)row * 512 + j] = f2bf(lrelu(v));
}

// ---------------- MFMA GEMM: C = lrelu(A @ Bt^T + bias), bf16 in/out, f32 accum ----
// A: M x K bf16 row-major. Bt: N x K bf16 row-major. 64x64 tile, 4 waves (2x2 of 32x32).
// MODE 0: C[row*ldc+col]. MODE 1: hero scatter into X. MODE 2: board scatter into X.
template<int MODE>
__global__ __launch_bounds__(256) void gemm_bt(const ushort* __restrict__ A,
                                               const ushort* __restrict__ Bt,
                                               const float* __restrict__ bias, int biasN,
                                               ushort* __restrict__ C,
                                               int M_, int N_, int K_, int ldc) {
    __shared__ __align__(16) ushort As[64][72];
    __shared__ __align__(16) ushort Bs[64][72];
    const int row0 = blockIdx.x * 64, col0 = blockIdx.y * 64;
    const int tid = threadIdx.x, lane = tid & 63, wave = tid >> 6;
    const int wr = (wave >> 1) * 32, wc = (wave & 1) * 32;
    const int lr = lane & 15, khalf = (lane >> 4) * 8;
    f32x4 acc[2][2] = {};
    for (int k0 = 0; k0 < K_; k0 += 64) {
        #pragma unroll
        for (int s2 = 0; s2 < 2; ++s2) {
            int g = tid + s2 * 256;
            int r = g >> 3, gc = (g & 7) * 8;
            *(short8*)(&As[r][gc]) = *(const short8*)(A  + (size_t)(row0 + r) * K_ + k0 + gc);
            *(short8*)(&Bs[r][gc]) = *(const short8*)(Bt + (size_t)(col0 + r) * K_ + k0 + gc);
        }
        __syncthreads();
        #pragma unroll
        for (int kk = 0; kk < 64; kk += 32) {
            short8 a0 = *(const short8*)(&As[wr + lr][kk + khalf]);
            short8 a1 = *(const short8*)(&As[wr + 16 + lr][kk + khalf]);
            short8 b0 = *(const short8*)(&Bs[wc + lr][kk + khalf]);
            short8 b1 = *(const short8*)(&Bs[wc + 16 + lr][kk + khalf]);
            acc[0][0] = __builtin_amdgcn_mfma_f32_16x16x32_bf16(a0, b0, acc[0][0], 0, 0, 0);
            acc[0][1] = __builtin_amdgcn_mfma_f32_16x16x32_bf16(a0, b1, acc[0][1], 0, 0, 0);
            acc[1][0] = __builtin_amdgcn_mfma_f32_16x16x32_bf16(a1, b0, acc[1][0], 0, 0, 0);
            acc[1][1] = __builtin_amdgcn_mfma_f32_16x16x32_bf16(a1, b1, acc[1][1], 0, 0, 0);
        }
        __syncthreads();
    }
    #pragma unroll
    for (int i = 0; i < 2; ++i)
    #pragma unroll
    for (int j = 0; j < 2; ++j)
    #pragma unroll
    for (int q = 0; q < 4; ++q) {
        int row = row0 + wr + i * 16 + (lane >> 4) * 4 + q;
        int col = col0 + wc + j * 16 + (lane & 15);
        float v = acc[i][j][q] + ((col < biasN) ? bias[col] : 0.f);
        v = lrelu(v);
        size_t off;
        if (MODE == 0)      off = (size_t)row * ldc + col;
        else if (MODE == 1) off = (size_t)(row / 6) * 2048 + (size_t)(row % 6) * 128 + col;
        else                off = (size_t)(row / 10) * 2048 + 768 + (size_t)(row % 10) * 128 + col;
        C[off] = f2bf(v);
    }
}

// ---------------- final: out[m][a] = R3[m,:127] @ sW + sb ----------------
__global__ void out_kernel(const ushort* __restrict__ R3, const float* __restrict__ sW,
                           const float* __restrict__ sb, float* __restrict__ out, int M) {
    int idx = blockIdx.x * 256 + threadIdx.x;
    if (idx >= M * 9) return;
    int m = idx / 9, a = idx % 9;
    float acc = sb[a];
    for (int n = 0; n < 127; ++n) acc += bf2f(R3[(size_t)m * 128 + n]) * sW[n * 9 + a];
    out[idx] = acc;
}

extern "C" void kernel_launch(void* const* d_in, const int* in_sizes, int n_in,
                              void* d_out, int out_size, void* d_ws, size_t ws_size,
                              hipStream_t stream) {
    const int*   x    = (const int*)  d_in[0];
    const float* emb  = (const float*)d_in[1];
    const float* hW1  = (const float*)d_in[2];
    const float* hb1  = (const float*)d_in[3];
    const float* hW2  = (const float*)d_in[4];
    const float* hb2  = (const float*)d_in[5];
    const float* bW1  = (const float*)d_in[6];
    const float* bb1  = (const float*)d_in[7];
    const float* bW2  = (const float*)d_in[8];
    const float* bb2  = (const float*)d_in[9];
    const float* oW1  = (const float*)d_in[10];
    const float* ob1  = (const float*)d_in[11];
    const float* oW2  = (const float*)d_in[12];
    const float* ob2  = (const float*)d_in[13];
    const float* oW3  = (const float*)d_in[14];
    const float* ob3  = (const float*)d_in[15];
    const float* sW   = (const float*)d_in[16];
    const float* sb   = (const float*)d_in[17];

    char* ws = (char*)d_ws;
    // byte offsets (all 256B aligned)
    constexpr size_t OFF_T    = 0;                       // 5*53*512 f32     = 542,720
    constexpr size_t OFF_HW2T = 542720;                  // 128x512 bf16     = 131,072
    constexpr size_t OFF_BW2T = OFF_HW2T + 131072;
    constexpr size_t OFF_OW2T = OFF_BW2T + 131072;       // 256x512 bf16     = 262,144
    constexpr size_t OFF_OW3T = OFF_OW2T + 262144;       // 128x256 bf16     = 65,536
    constexpr size_t OFF_WCT  = OFF_OW3T + 65536;        // 512x2048 bf16    = 2,097,152
    constexpr size_t OFF_CID  = OFF_WCT + 2097152;       // 2048x9 i32       = 73,728
    constexpr size_t OFF_AH   = OFF_CID + 73728;         // 12288x512 bf16   = 12,582,912
    constexpr size_t OFF_AB   = OFF_AH + 12582912;       // 20480x512 bf16   = 20,971,520
    constexpr size_t OFF_X    = OFF_AB + 20971520;       // 2048x2048 bf16   = 8,388,608
    constexpr size_t OFF_R1   = OFF_X + 8388608;         // 2048x512 bf16    = 2,097,152
    constexpr size_t OFF_R2   = OFF_R1 + 2097152;        // 2048x256 bf16    = 1,048,576
    constexpr size_t OFF_R3   = OFF_R2 + 1048576;        // 2048x128 bf16    = 524,288

    float*  T    = (float*)(ws + OFF_T);
    ushort* hW2t = (ushort*)(ws + OFF_HW2T);
    ushort* bW2t = (ushort*)(ws + OFF_BW2T);
    ushort* oW2t = (ushort*)(ws + OFF_OW2T);
    ushort* oW3t = (ushort*)(ws + OFF_OW3T);
    ushort* Wct  = (ushort*)(ws + OFF_WCT);
    int*    cid  = (int*)(ws + OFF_CID);
    ushort* Ah   = (ushort*)(ws + OFF_AH);
    ushort* Ab   = (ushort*)(ws + OFF_AB);
    ushort* X    = (ushort*)(ws + OFF_X);
    ushort* R1   = (ushort*)(ws + OFF_R1);
    ushort* R2   = (ushort*)(ws + OFF_R2);
    ushort* R3   = (ushort*)(ws + OFF_R3);

    // ---- prep (input-dependent only on weights) ----
    prep_T<<<265, 512, 0, stream>>>(emb, hW1, bW1, T);
    transpose_bf16<<<(128*512 + 255)/256, 256, 0, stream>>>(hW2, hW2t, 512, 128, 128);
    transpose_bf16<<<(128*512 + 255)/256, 256, 0, stream>>>(bW2, bW2t, 512, 128, 128);
    transpose_bf16<<<(256*512 + 255)/256, 256, 0, stream>>>(oW2, oW2t, 512, 256, 256);
    transpose_bf16<<<(128*256 + 255)/256, 256, 0, stream>>>(oW3, oW3t, 256, 127, 128);
    prep_Wct<<<dim3(32, 8), 256, 0, stream>>>(oW1, Wct);

    // ---- per-row pipeline ----
    cards_kernel<<<(M_ROWS + 255)/256, 256, 0, stream>>>(x, cid, M_ROWS);
    build_Ah<<<M_ROWS * 6, 512, 0, stream>>>(cid, T, hb1, Ah);
    build_Ab<<<M_ROWS * 10, 512, 0, stream>>>(cid, T, bb1, Ab);

    // hero layer-2 -> X[:, p*128 : ...]
    gemm_bt<1><<<dim3(M_ROWS*6/64, 2), 256, 0, stream>>>(Ah, hW2t, hb2, 128, X, M_ROWS*6, 128, 512, 0);
    // board layer-2 -> X[:, 768 + t*128 : ...]
    gemm_bt<2><<<dim3(M_ROWS*10/64, 2), 256, 0, stream>>>(Ab, bW2t, bb2, 128, X, M_ROWS*10, 128, 512, 0);
    // combine: R1 = lrelu(X @ Wc + ob1)
    gemm_bt<0><<<dim3(M_ROWS/64, 8), 256, 0, stream>>>(X, Wct, ob1, 512, R1, M_ROWS, 512, 2048, 512);
    // R2 = lrelu(R1 @ oW2 + ob2)
    gemm_bt<0><<<dim3(M_ROWS/64, 4), 256, 0, stream>>>(R1, oW2t, ob2, 256, R2, M_ROWS, 256, 512, 256);
    // R3 = lrelu(R2 @ oW3 + ob3)  (col 127 zero-padded)
    gemm_bt<0><<<dim3(M_ROWS/64, 2), 256, 0, stream>>>(R2, oW3t, ob3, 127, R3, M_ROWS, 128, 256, 128);
    // out = R3 @ sW + sb
    out_kernel<<<(M_ROWS*9 + 255)/256, 256, 0, stream>>>(R3, sW, sb, (float*)d_out, M_ROWS);
}

// Round 2
// 111.445 us; speedup vs baseline: 1.6959x; 1.6959x over previous
//
#include <hip/hip_runtime.h>

typedef __attribute__((ext_vector_type(8))) short short8;
typedef __attribute__((ext_vector_type(4))) float f32x4;

__device__ inline float lrelu(float v){ return v > 0.f ? v : 0.01f*v; }
__device__ inline ushort f2bf(float f){
    unsigned u = __float_as_uint(f);
    return (ushort)((u + 0x7fffu + ((u >> 16) & 1u)) >> 16);
}
__device__ inline float bf2f(ushort h){ return __uint_as_float(((unsigned)h) << 16); }

__device__ __forceinline__ void gload16(const void* gp, void* lp) {
    __builtin_amdgcn_global_load_lds(
        (const __attribute__((address_space(1))) unsigned int*)gp,
        (__attribute__((address_space(3))) unsigned int*)lp,
        16, 0, 0);
}

#define M_ROWS 2048

// ---------------- prep: T[slot][card][512] = emb[card] @ Wslice (+ folded bias) ----
// slots: 0,1 = hW1 rows 0-63,64-127 ; 2,3,4 = bW1 rows 0-63,64-127,128-191
// hb1 folded into slot 1, bb1 folded into slot 4. T[0][0][:] == 0 (emb row 0 is zero).
__global__ __launch_bounds__(512) void prep_T(const float* __restrict__ emb,
                                              const float* __restrict__ hW1,
                                              const float* __restrict__ bW1,
                                              const float* __restrict__ hb1,
                                              const float* __restrict__ bb1,
                                              float* __restrict__ T) {
    int b = blockIdx.x;          // slot*53 + card, 265 blocks
    int slot = b / 53, card = b % 53;
    const float* W = (slot < 2) ? (hW1 + slot * 64 * 512) : (bW1 + (slot - 2) * 64 * 512);
    int j = threadIdx.x;
    const float* e = emb + card * 64;
    float acc = (slot == 1) ? hb1[j] : ((slot == 4) ? bb1[j] : 0.f);
    #pragma unroll 8
    for (int k = 0; k < 64; ++k) acc += e[k] * W[k * 512 + j];
    T[(size_t)b * 512 + j] = acc;
}

// ---------------- prep: transpose+convert weights to bf16 (N x K), zero-pad rows ----
__global__ void transpose_bf16(const float* __restrict__ in, ushort* __restrict__ out,
                               int K, int Nin, int Nout) {
    size_t idx = (size_t)blockIdx.x * 256 + threadIdx.x;
    if (idx >= (size_t)Nout * K) return;
    int n = (int)(idx / K), k = (int)(idx % K);
    float v = (n < Nin) ? in[(size_t)k * Nin + n] : 0.f;
    out[idx] = f2bf(v);
}

// ---------------- prep: Wct[512][2048] = transposed block-sum of oW1 ----------------
__global__ __launch_bounds__(256) void prep_Wct(const float* __restrict__ oW1,
                                                ushort* __restrict__ Wct) {
    __shared__ float tile[64][65];
    int kb = blockIdx.x;  // 0..31 over 2048 (X columns)
    int nb = blockIdx.y;  // 0..7  over 512  (R1 columns)
    int tid = threadIdx.x;
    int nl = tid & 63;
    for (int kl = tid >> 6; kl < 64; kl += 4) {
        int col = kb * 64 + kl;         // 0..2047
        int p = col >> 7, r = col & 127;
        int n = nb * 64 + nl;
        float s = 0.f;
        if (p < 6) {
            #pragma unroll
            for (int j = 0; j < 10; ++j) s += oW1[(size_t)((p * 10 + j) * 256 + r) * 512 + n];
        } else {
            int t = p - 6;
            #pragma unroll
            for (int i = 0; i < 6; ++i) s += oW1[(size_t)((i * 10 + t) * 256 + 128 + r) * 512 + n];
        }
        tile[kl][nl] = s;
    }
    __syncthreads();
    for (int nl2 = tid >> 6; nl2 < 64; nl2 += 4) {
        int kl2 = tid & 63;
        Wct[(size_t)(nb * 64 + nl2) * 2048 + kb * 64 + kl2] = f2bf(tile[kl2][nl2]);
    }
}

// ---------------- cards: parse, sort hero(4)/board(5) by (rank,suit), card id ----
__global__ void cards_kernel(const int* __restrict__ x, int* __restrict__ cid, int M) {
    int m = blockIdx.x * blockDim.x + threadIdx.x;
    if (m >= M) return;
    int kh[4], kb[5];
    #pragma unroll
    for (int i = 0; i < 4; ++i) { int r = x[m*18 + 2*i], s = x[m*18 + 2*i + 1]; kh[i] = r*8 + s; }
    #pragma unroll
    for (int i = 0; i < 5; ++i) { int r = x[m*18 + 8 + 2*i], s = x[m*18 + 9 + 2*i]; kb[i] = r*8 + s; }
    #pragma unroll
    for (int i = 1; i < 4; ++i) { int v = kh[i], j = i-1; while (j >= 0 && kh[j] > v) { kh[j+1]=kh[j]; --j; } kh[j+1]=v; }
    #pragma unroll
    for (int i = 1; i < 5; ++i) { int v = kb[i], j = i-1; while (j >= 0 && kb[j] > v) { kb[j+1]=kb[j]; --j; } kb[j+1]=v; }
    #pragma unroll
    for (int i = 0; i < 4; ++i) { int r = kh[i] >> 3, s = kh[i] & 7; cid[m*9 + i] = (r - 1) * s; }
    #pragma unroll
    for (int i = 0; i < 5; ++i) { int r = kb[i] >> 3, s = kb[i] & 7; cid[m*9 + 4 + i] = (r - 1) * s; }
}

// ---------------- fused layer-1-build + layer-2 GEMM, scatter into X ----------------
// blocks [0,192): hero rows (12288, 64/block). blocks [192,512): board rows (20480).
// Tile 64 rows x 128 cols (full N), K=512. 4 waves, each 64 rows x 32 cols (4x2 frags).
__global__ __launch_bounds__(256) void l2_fused(const int* __restrict__ cid,
                                                const float* __restrict__ T,
                                                const ushort* __restrict__ hW2t,
                                                const ushort* __restrict__ bW2t,
                                                const float* __restrict__ hb2,
                                                const float* __restrict__ bb2,
                                                ushort* __restrict__ X) {
    __shared__ __align__(16) ushort As[64][72];      // padded: reg-built
    __shared__ __align__(16) ushort Bs[128 * 64];    // linear: global_load_lds dest
    const int bid = blockIdx.x;
    const bool hero = bid < 192;
    const int row0 = hero ? bid * 64 : (bid - 192) * 64;
    const ushort* Bt = hero ? hW2t : bW2t;
    const float* bias = hero ? hb2 : bb2;
    const int tid = threadIdx.x, lane = tid & 63, wave = tid >> 6;
    const int lr = lane & 15, kh = (lane >> 4) * 8;

    // A-build assignment: thread builds row br, 16-col chunk bc
    const int br = tid >> 2, bc = (tid & 3) * 16;
    const int grow = row0 + br;
    const float *t0, *t1, *t2;
    if (hero) {
        const int HP0[6] = {0,0,0,1,1,2}, HP1[6] = {1,2,3,2,3,3};
        int m = grow / 6, p = grow - m * 6;
        t0 = T + (size_t)(0*53 + cid[m*9 + HP0[p]]) * 512;
        t1 = T + (size_t)(1*53 + cid[m*9 + HP1[p]]) * 512;
        t2 = T;   // slot0 card0 == all zeros
    } else {
        const int BT0[10] = {4,4,4,4,4,4,5,5,5,6};
        const int BT1[10] = {5,5,5,6,6,7,6,6,7,7};
        const int BT2[10] = {6,7,8,7,8,8,7,8,8,8};
        int m = grow / 10, t = grow - m * 10;
        t0 = T + (size_t)(2*53 + cid[m*9 + BT0[t]]) * 512;
        t1 = T + (size_t)(3*53 + cid[m*9 + BT1[t]]) * 512;
        t2 = T + (size_t)(4*53 + cid[m*9 + BT2[t]]) * 512;
    }

    f32x4 acc[4][2] = {};
    for (int k0 = 0; k0 < 512; k0 += 64) {
        // stage B tile (128x64 bf16 = 16KB) via global_load_lds: 16 chunks of 1KB
        #pragma unroll
        for (int c = 0; c < 4; ++c) {
            int q = wave * 4 + c;                       // 0..15 -> rows [q*8, q*8+8)
            int r = q * 8 + (lane >> 3);
            gload16(Bt + (size_t)r * 512 + k0 + (lane & 7) * 8, (void*)&Bs[q * 512]);
        }
        // build A tile (64x64) from gathered T rows
        #pragma unroll
        for (int h = 0; h < 2; ++h) {
            int kc = bc + h * 8;
            const f32x4* q0 = (const f32x4*)(t0 + k0 + kc);
            const f32x4* q1 = (const f32x4*)(t1 + k0 + kc);
            const f32x4* q2 = (const f32x4*)(t2 + k0 + kc);
            f32x4 u0 = q0[0], u1 = q1[0], u2 = q2[0];
            f32x4 v0 = q0[1], v1 = q1[1], v2 = q2[1];
            short8 pk;
            #pragma unroll
            for (int j = 0; j < 4; ++j) {
                float s = u0[j] + u1[j] + u2[j];
                pk[j] = (short)f2bf(lrelu(s));
            }
            #pragma unroll
            for (int j = 0; j < 4; ++j) {
                float s = v0[j] + v1[j] + v2[j];
                pk[4 + j] = (short)f2bf(lrelu(s));
            }
            *(short8*)&As[br][kc] = pk;
        }
        __syncthreads();
        #pragma unroll
        for (int kk = 0; kk < 64; kk += 32) {
            short8 a[4], b[2];
            #pragma unroll
            for (int g = 0; g < 4; ++g) a[g] = *(const short8*)&As[g*16 + lr][kk + kh];
            #pragma unroll
            for (int j = 0; j < 2; ++j) b[j] = *(const short8*)&Bs[(wave*32 + j*16 + lr)*64 + kk + kh];
            #pragma unroll
            for (int g = 0; g < 4; ++g)
                #pragma unroll
                for (int j = 0; j < 2; ++j)
                    acc[g][j] = __builtin_amdgcn_mfma_f32_16x16x32_bf16(a[g], b[j], acc[g][j], 0, 0, 0);
        }
        __syncthreads();
    }
    // epilogue: bias + lrelu + scatter into X
    #pragma unroll
    for (int g = 0; g < 4; ++g)
    #pragma unroll
    for (int j = 0; j < 2; ++j)
    #pragma unroll
    for (int q = 0; q < 4; ++q) {
        int row = row0 + g*16 + (lane >> 4)*4 + q;
        int col = wave*32 + j*16 + (lane & 15);
        float v = acc[g][j][q] + bias[col];
        v = lrelu(v);
        size_t off;
        if (hero) { int m = row / 6,  p = row - m*6;  off = (size_t)m*2048 + p*128 + col; }
        else      { int m = row / 10, p = row - m*10; off = (size_t)m*2048 + 768 + p*128 + col; }
        X[off] = f2bf(v);
    }
}

// ---------------- generic MFMA GEMM: C = lrelu(A @ Bt^T + bias), 64x64 tile ----------
// A: M x K bf16 row-major. Bt: N x K bf16 row-major. 4 waves (2x2 of 32x32).
__global__ __launch_bounds__(256) void gemm64(const ushort* __restrict__ A,
                                              const ushort* __restrict__ Bt,
                                              const float* __restrict__ bias, int biasN,
                                              ushort* __restrict__ C,
                                              int K_, int ldc) {
    __shared__ __align__(16) ushort As[64 * 64];
    __shared__ __align__(16) ushort Bs[64 * 64];
    const int row0 = blockIdx.x * 64, col0 = blockIdx.y * 64;
    const int tid = threadIdx.x, lane = tid & 63, wave = tid >> 6;
    const int wr = (wave >> 1) * 32, wc = (wave & 1) * 32;
    const int lr = lane & 15, kh = (lane >> 4) * 8;
    const int srow = lane >> 3, scol = (lane & 7) * 8;
    f32x4 acc[2][2] = {};
    for (int k0 = 0; k0 < K_; k0 += 64) {
        #pragma unroll
        for (int c = 0; c < 2; ++c) {
            int q = wave * 2 + c;                    // 0..7 -> rows [q*8, q*8+8)
            int r = q * 8 + srow;
            gload16(A  + (size_t)(row0 + r) * K_ + k0 + scol, (void*)&As[q * 512]);
            gload16(Bt + (size_t)(col0 + r) * K_ + k0 + scol, (void*)&Bs[q * 512]);
        }
        __syncthreads();
        #pragma unroll
        for (int kk = 0; kk < 64; kk += 32) {
            short8 a0 = *(const short8*)&As[(wr + lr)*64 + kk + kh];
            short8 a1 = *(const short8*)&As[(wr + 16 + lr)*64 + kk + kh];
            short8 b0 = *(const short8*)&Bs[(wc + lr)*64 + kk + kh];
            short8 b1 = *(const short8*)&Bs[(wc + 16 + lr)*64 + kk + kh];
            acc[0][0] = __builtin_amdgcn_mfma_f32_16x16x32_bf16(a0, b0, acc[0][0], 0, 0, 0);
            acc[0][1] = __builtin_amdgcn_mfma_f32_16x16x32_bf16(a0, b1, acc[0][1], 0, 0, 0);
            acc[1][0] = __builtin_amdgcn_mfma_f32_16x16x32_bf16(a1, b0, acc[1][0], 0, 0, 0);
            acc[1][1] = __builtin_amdgcn_mfma_f32_16x16x32_bf16(a1, b1, acc[1][1], 0, 0, 0);
        }
        __syncthreads();
    }
    #pragma unroll
    for (int i = 0; i < 2; ++i)
    #pragma unroll
    for (int j = 0; j < 2; ++j)
    #pragma unroll
    for (int q = 0; q < 4; ++q) {
        int row = row0 + wr + i*16 + (lane >> 4)*4 + q;
        int col = col0 + wc + j*16 + (lane & 15);
        float v = acc[i][j][q] + ((col < biasN) ? bias[col] : 0.f);
        C[(size_t)row * ldc + col] = f2bf(lrelu(v));
    }
}

// ---------------- final: out[m][a] = R3[m,:127] @ sW + sb ----------------
__global__ void out_kernel(const ushort* __restrict__ R3, const float* __restrict__ sW,
                           const float* __restrict__ sb, float* __restrict__ out, int M) {
    int idx = blockIdx.x * 256 + threadIdx.x;
    if (idx >= M * 9) return;
    int m = idx / 9, a = idx % 9;
    float acc = sb[a];
    for (int n = 0; n < 127; ++n) acc += bf2f(R3[(size_t)m * 128 + n]) * sW[n * 9 + a];
    out[idx] = acc;
}

extern "C" void kernel_launch(void* const* d_in, const int* in_sizes, int n_in,
                              void* d_out, int out_size, void* d_ws, size_t ws_size,
                              hipStream_t stream) {
    const int*   x    = (const int*)  d_in[0];
    const float* emb  = (const float*)d_in[1];
    const float* hW1  = (const float*)d_in[2];
    const float* hb1  = (const float*)d_in[3];
    const float* hW2  = (const float*)d_in[4];
    const float* hb2  = (const float*)d_in[5];
    const float* bW1  = (const float*)d_in[6];
    const float* bb1  = (const float*)d_in[7];
    const float* bW2  = (const float*)d_in[8];
    const float* bb2  = (const float*)d_in[9];
    const float* oW1  = (const float*)d_in[10];
    const float* ob1  = (const float*)d_in[11];
    const float* oW2  = (const float*)d_in[12];
    const float* ob2  = (const float*)d_in[13];
    const float* oW3  = (const float*)d_in[14];
    const float* ob3  = (const float*)d_in[15];
    const float* sW   = (const float*)d_in[16];
    const float* sb   = (const float*)d_in[17];

    char* ws = (char*)d_ws;
    constexpr size_t OFF_T    = 0;                     // 5*53*512 f32  = 542,720
    constexpr size_t OFF_HW2T = 542720;                // 128x512 bf16  = 131,072
    constexpr size_t OFF_BW2T = OFF_HW2T + 131072;
    constexpr size_t OFF_OW2T = OFF_BW2T + 131072;     // 256x512 bf16  = 262,144
    constexpr size_t OFF_OW3T = OFF_OW2T + 262144;     // 128x256 bf16  = 65,536
    constexpr size_t OFF_WCT  = OFF_OW3T + 65536;      // 512x2048 bf16 = 2,097,152
    constexpr size_t OFF_CID  = OFF_WCT + 2097152;     // 2048x9 i32    = 73,728
    constexpr size_t OFF_X    = OFF_CID + 73728;       // 2048x2048 bf16= 8,388,608
    constexpr size_t OFF_R1   = OFF_X + 8388608;       // 2048x512 bf16 = 2,097,152
    constexpr size_t OFF_R2   = OFF_R1 + 2097152;      // 2048x256 bf16 = 1,048,576
    constexpr size_t OFF_R3   = OFF_R2 + 1048576;      // 2048x128 bf16 = 524,288

    float*  T    = (float*)(ws + OFF_T);
    ushort* hW2t = (ushort*)(ws + OFF_HW2T);
    ushort* bW2t = (ushort*)(ws + OFF_BW2T);
    ushort* oW2t = (ushort*)(ws + OFF_OW2T);
    ushort* oW3t = (ushort*)(ws + OFF_OW3T);
    ushort* Wct  = (ushort*)(ws + OFF_WCT);
    int*    cid  = (int*)(ws + OFF_CID);
    ushort* X    = (ushort*)(ws + OFF_X);
    ushort* R1   = (ushort*)(ws + OFF_R1);
    ushort* R2   = (ushort*)(ws + OFF_R2);
    ushort* R3   = (ushort*)(ws + OFF_R3);

    // ---- prep ----
    prep_T<<<265, 512, 0, stream>>>(emb, hW1, bW1, hb1, bb1, T);
    transpose_bf16<<<(128*512 + 255)/256, 256, 0, stream>>>(hW2, hW2t, 512, 128, 128);
    transpose_bf16<<<(128*512 + 255)/256, 256, 0, stream>>>(bW2, bW2t, 512, 128, 128);
    transpose_bf16<<<(256*512 + 255)/256, 256, 0, stream>>>(oW2, oW2t, 512, 256, 256);
    transpose_bf16<<<(128*256 + 255)/256, 256, 0, stream>>>(oW3, oW3t, 256, 127, 128);
    prep_Wct<<<dim3(32, 8), 256, 0, stream>>>(oW1, Wct);

    // ---- per-row pipeline ----
    cards_kernel<<<(M_ROWS + 255)/256, 256, 0, stream>>>(x, cid, M_ROWS);
    l2_fused<<<512, 256, 0, stream>>>(cid, T, hW2t, bW2t, hb2, bb2, X);
    // combine: R1 = lrelu(X @ Wc + ob1)
    gemm64<<<dim3(32, 8), 256, 0, stream>>>(X, Wct, ob1, 512, R1, 2048, 512);
    // R2 = lrelu(R1 @ oW2 + ob2)
    gemm64<<<dim3(32, 4), 256, 0, stream>>>(R1, oW2t, ob2, 256, R2, 512, 256);
    // R3 = lrelu(R2 @ oW3 + ob3)
    gemm64<<<dim3(32, 2), 256, 0, stream>>>(R2, oW3t, ob3, 127, R3, 256, 128);
    // out = R3 @ sW + sb
    out_kernel<<<(M_ROWS*9 + 255)/256, 256, 0, stream>>>(R3, sW, sb, (float*)d_out, M_ROWS);
}

// Round 3
// 83.471 us; speedup vs baseline: 2.2643x; 1.3351x over previous
//
#include <hip/hip_runtime.h>

typedef __attribute__((ext_vector_type(8))) short short8;
typedef __attribute__((ext_vector_type(4))) float f32x4;

__device__ inline float lrelu(float v){ return v > 0.f ? v : 0.01f*v; }
__device__ inline ushort f2bf(float f){
    unsigned u = __float_as_uint(f);
    return (ushort)((u + 0x7fffu + ((u >> 16) & 1u)) >> 16);
}
__device__ inline float bf2f(ushort h){ return __uint_as_float(((unsigned)h) << 16); }

__device__ __forceinline__ void gload16(const void* gp, void* lp) {
    __builtin_amdgcn_global_load_lds(
        (const __attribute__((address_space(1))) unsigned int*)gp,
        (__attribute__((address_space(3))) unsigned int*)lp,
        16, 0, 0);
}

#define M_ROWS 2048

// ================= prep_all: every input-only transform in one launch =================
// block ranges:
//   [0,265)        prep_T   : T[slot][card][512] = emb[card] @ Wslice (+bias folded)
//   [265,393)      hW2t     : transpose->bf16 128x512
//   [393,521)      bW2t     : transpose->bf16 128x512
//   [521,777)      oW2t     : transpose->bf16 256x512
//   [777,841)      oW3t     : transpose->bf16 128x256 (row 127 zero-pad)
//   [841,1097)     prep_Wct : Wct[512][2048] block-sum-transpose of oW1
//   [1097,1101)    cards    : parse+sort -> cid
#define PB_T    0
#define PB_HW2  265
#define PB_BW2  393
#define PB_OW2  521
#define PB_OW3  777
#define PB_WCT  841
#define PB_CARD 1097
#define PB_END  1101

__device__ void d_transpose(const float* __restrict__ in, ushort* __restrict__ out,
                            int K, int Nin, int Nout, int b, int tid) {
    int idx = b * 512 + tid;
    if (idx >= Nout * K) return;
    int n = idx / K, k = idx - n * K;
    float v = (n < Nin) ? in[(size_t)k * Nin + n] : 0.f;
    out[idx] = f2bf(v);
}

__global__ __launch_bounds__(512) void prep_all(const int* __restrict__ x,
                                                const float* __restrict__ emb,
                                                const float* __restrict__ hW1,
                                                const float* __restrict__ hb1,
                                                const float* __restrict__ hW2,
                                                const float* __restrict__ bW1,
                                                const float* __restrict__ bb1,
                                                const float* __restrict__ bW2,
                                                const float* __restrict__ oW1,
                                                const float* __restrict__ oW2,
                                                const float* __restrict__ oW3,
                                                float* __restrict__ T,
                                                ushort* __restrict__ hW2t,
                                                ushort* __restrict__ bW2t,
                                                ushort* __restrict__ oW2t,
                                                ushort* __restrict__ oW3t,
                                                ushort* __restrict__ Wct,
                                                int* __restrict__ cid) {
    const int bid = blockIdx.x, tid = threadIdx.x;
    if (bid < PB_HW2) {
        // ---- prep_T ----
        int b = bid;                 // slot*53 + card
        int slot = b / 53, card = b - slot * 53;
        const float* W = (slot < 2) ? (hW1 + slot * 64 * 512) : (bW1 + (slot - 2) * 64 * 512);
        const float* e = emb + card * 64;
        float acc = (slot == 1) ? hb1[tid] : ((slot == 4) ? bb1[tid] : 0.f);
        #pragma unroll 8
        for (int k = 0; k < 64; ++k) acc += e[k] * W[k * 512 + tid];
        T[(size_t)b * 512 + tid] = acc;
    } else if (bid < PB_BW2) {
        d_transpose(hW2, hW2t, 512, 128, 128, bid - PB_HW2, tid);
    } else if (bid < PB_OW2) {
        d_transpose(bW2, bW2t, 512, 128, 128, bid - PB_BW2, tid);
    } else if (bid < PB_OW3) {
        d_transpose(oW2, oW2t, 512, 256, 256, bid - PB_OW2, tid);
    } else if (bid < PB_WCT) {
        d_transpose(oW3, oW3t, 256, 127, 128, bid - PB_OW3, tid);
    } else if (bid < PB_CARD) {
        // ---- prep_Wct ----
        __shared__ float tile[64][65];
        int b = bid - PB_WCT;
        int kb = b & 31, nb = b >> 5;      // kb over 2048/64, nb over 512/64
        int nl = tid & 63;
        for (int kl = tid >> 6; kl < 64; kl += 8) {
            int col = kb * 64 + kl;
            int p = col >> 7, r = col & 127;
            int n = nb * 64 + nl;
            float s = 0.f;
            if (p < 6) {
                #pragma unroll
                for (int j = 0; j < 10; ++j) s += oW1[(size_t)((p * 10 + j) * 256 + r) * 512 + n];
            } else {
                int t = p - 6;
                #pragma unroll
                for (int i = 0; i < 6; ++i) s += oW1[(size_t)((i * 10 + t) * 256 + 128 + r) * 512 + n];
            }
            tile[kl][nl] = s;
        }
        __syncthreads();
        for (int nl2 = tid >> 6; nl2 < 64; nl2 += 8) {
            int kl2 = tid & 63;
            Wct[(size_t)(nb * 64 + nl2) * 2048 + kb * 64 + kl2] = f2bf(tile[kl2][nl2]);
        }
    } else {
        // ---- cards ----
        int m = (bid - PB_CARD) * 512 + tid;
        if (m >= M_ROWS) return;
        int kh[4], kb[5];
        #pragma unroll
        for (int i = 0; i < 4; ++i) { int r = x[m*18 + 2*i], s = x[m*18 + 2*i + 1]; kh[i] = r*8 + s; }
        #pragma unroll
        for (int i = 0; i < 5; ++i) { int r = x[m*18 + 8 + 2*i], s = x[m*18 + 9 + 2*i]; kb[i] = r*8 + s; }
        #pragma unroll
        for (int i = 1; i < 4; ++i) { int v = kh[i], j = i-1; while (j >= 0 && kh[j] > v) { kh[j+1]=kh[j]; --j; } kh[j+1]=v; }
        #pragma unroll
        for (int i = 1; i < 5; ++i) { int v = kb[i], j = i-1; while (j >= 0 && kb[j] > v) { kb[j+1]=kb[j]; --j; } kb[j+1]=v; }
        #pragma unroll
        for (int i = 0; i < 4; ++i) { int r = kh[i] >> 3, s = kh[i] & 7; cid[m*9 + i] = (r - 1) * s; }
        #pragma unroll
        for (int i = 0; i < 5; ++i) { int r = kb[i] >> 3, s = kb[i] & 7; cid[m*9 + 4 + i] = (r - 1) * s; }
    }
}

// ======== fused layer-1-build + layer-2 GEMM, double-buffered, scatter into X ========
// blocks [0,192): hero rows (12288). blocks [192,512): board rows (20480).
// Tile 64 rows x 128 cols, K=512. 4 waves, each 64 rows x 32 cols (4x2 frags).
__global__ __launch_bounds__(256) void l2_fused(const int* __restrict__ cid,
                                                const float* __restrict__ T,
                                                const ushort* __restrict__ hW2t,
                                                const ushort* __restrict__ bW2t,
                                                const float* __restrict__ hb2,
                                                const float* __restrict__ bb2,
                                                ushort* __restrict__ X) {
    __shared__ __align__(16) ushort As[2][64][72];   // padded: reg-built
    __shared__ __align__(16) ushort Bs[2][128 * 64]; // linear: global_load_lds dest
    const int bid = blockIdx.x;
    const bool hero = bid < 192;
    const int row0 = hero ? bid * 64 : (bid - 192) * 64;
    const ushort* Bt = hero ? hW2t : bW2t;
    const float* bias = hero ? hb2 : bb2;
    const int tid = threadIdx.x, lane = tid & 63, wave = tid >> 6;
    const int lr = lane & 15, kh = (lane >> 4) * 8;

    // A-build: thread builds row br, 16-col chunk bc
    const int br = tid >> 2, bc = (tid & 3) * 16;
    const int grow = row0 + br;
    const float *t0, *t1, *t2;
    if (hero) {
        const int HP0[6] = {0,0,0,1,1,2}, HP1[6] = {1,2,3,2,3,3};
        int m = grow / 6, p = grow - m * 6;
        t0 = T + (size_t)(0*53 + cid[m*9 + HP0[p]]) * 512;
        t1 = T + (size_t)(1*53 + cid[m*9 + HP1[p]]) * 512;
        t2 = T;   // slot0 card0 == all zeros
    } else {
        const int BT0[10] = {4,4,4,4,4,4,5,5,5,6};
        const int BT1[10] = {5,5,5,6,6,7,6,6,7,7};
        const int BT2[10] = {6,7,8,7,8,8,7,8,8,8};
        int m = grow / 10, t = grow - m * 10;
        t0 = T + (size_t)(2*53 + cid[m*9 + BT0[t]]) * 512;
        t1 = T + (size_t)(3*53 + cid[m*9 + BT1[t]]) * 512;
        t2 = T + (size_t)(4*53 + cid[m*9 + BT2[t]]) * 512;
    }

    auto stageB = [&](int buf, int k0) {
        #pragma unroll
        for (int c = 0; c < 4; ++c) {
            int q = wave * 4 + c;                       // 16 chunks of 1KB
            int r = q * 8 + (lane >> 3);
            gload16(Bt + (size_t)r * 512 + k0 + (lane & 7) * 8, (void*)&Bs[buf][q * 512]);
        }
    };
    auto buildA = [&](int buf, int k0) {
        #pragma unroll
        for (int h = 0; h < 2; ++h) {
            int kc = bc + h * 8;
            const f32x4* q0 = (const f32x4*)(t0 + k0 + kc);
            const f32x4* q1 = (const f32x4*)(t1 + k0 + kc);
            const f32x4* q2 = (const f32x4*)(t2 + k0 + kc);
            f32x4 u0 = q0[0], u1 = q1[0], u2 = q2[0];
            f32x4 v0 = q0[1], v1 = q1[1], v2 = q2[1];
            short8 pk;
            #pragma unroll
            for (int j = 0; j < 4; ++j) pk[j] = (short)f2bf(lrelu(u0[j] + u1[j] + u2[j]));
            #pragma unroll
            for (int j = 0; j < 4; ++j) pk[4+j] = (short)f2bf(lrelu(v0[j] + v1[j] + v2[j]));
            *(short8*)&As[buf][br][kc] = pk;
        }
    };

    f32x4 acc[4][2] = {};
    stageB(0, 0); buildA(0, 0);
    __syncthreads();
    for (int t = 0; t < 8; ++t) {
        int cur = t & 1;
        if (t < 7) { stageB(cur ^ 1, (t + 1) * 64); buildA(cur ^ 1, (t + 1) * 64); }
        #pragma unroll
        for (int kk = 0; kk < 64; kk += 32) {
            short8 a[4], b[2];
            #pragma unroll
            for (int g = 0; g < 4; ++g) a[g] = *(const short8*)&As[cur][g*16 + lr][kk + kh];
            #pragma unroll
            for (int j = 0; j < 2; ++j) b[j] = *(const short8*)&Bs[cur][(wave*32 + j*16 + lr)*64 + kk + kh];
            #pragma unroll
            for (int g = 0; g < 4; ++g)
                #pragma unroll
                for (int j = 0; j < 2; ++j)
                    acc[g][j] = __builtin_amdgcn_mfma_f32_16x16x32_bf16(a[g], b[j], acc[g][j], 0, 0, 0);
        }
        __syncthreads();
    }
    #pragma unroll
    for (int g = 0; g < 4; ++g)
    #pragma unroll
    for (int j = 0; j < 2; ++j)
    #pragma unroll
    for (int q = 0; q < 4; ++q) {
        int row = row0 + g*16 + (lane >> 4)*4 + q;
        int col = wave*32 + j*16 + (lane & 15);
        float v = lrelu(acc[g][j][q] + bias[col]);
        size_t off;
        if (hero) { int m = row / 6,  p = row - m*6;  off = (size_t)m*2048 + p*128 + col; }
        else      { int m = row / 10, p = row - m*10; off = (size_t)m*2048 + 768 + p*128 + col; }
        X[off] = f2bf(v);
    }
}

// ========== generic MFMA GEMM, double-buffered: C = lrelu(A @ Bt^T + bias) ==========
__global__ __launch_bounds__(256) void gemm64(const ushort* __restrict__ A,
                                              const ushort* __restrict__ Bt,
                                              const float* __restrict__ bias, int biasN,
                                              ushort* __restrict__ C,
                                              int K_, int ldc) {
    __shared__ __align__(16) ushort As[2][64 * 64];
    __shared__ __align__(16) ushort Bs[2][64 * 64];
    const int row0 = blockIdx.x * 64, col0 = blockIdx.y * 64;
    const int tid = threadIdx.x, lane = tid & 63, wave = tid >> 6;
    const int wr = (wave >> 1) * 32, wc = (wave & 1) * 32;
    const int lr = lane & 15, kh = (lane >> 4) * 8;
    const int srow = lane >> 3, scol = (lane & 7) * 8;

    auto stage = [&](int buf, int k0) {
        #pragma unroll
        for (int c = 0; c < 2; ++c) {
            int q = wave * 2 + c;
            int r = q * 8 + srow;
            gload16(A  + (size_t)(row0 + r) * K_ + k0 + scol, (void*)&As[buf][q * 512]);
            gload16(Bt + (size_t)(col0 + r) * K_ + k0 + scol, (void*)&Bs[buf][q * 512]);
        }
    };

    f32x4 acc[2][2] = {};
    stage(0, 0);
    __syncthreads();
    const int nt = K_ >> 6;
    for (int t = 0; t < nt; ++t) {
        int cur = t & 1;
        if (t + 1 < nt) stage(cur ^ 1, (t + 1) * 64);
        #pragma unroll
        for (int kk = 0; kk < 64; kk += 32) {
            short8 a0 = *(const short8*)&As[cur][(wr + lr)*64 + kk + kh];
            short8 a1 = *(const short8*)&As[cur][(wr + 16 + lr)*64 + kk + kh];
            short8 b0 = *(const short8*)&Bs[cur][(wc + lr)*64 + kk + kh];
            short8 b1 = *(const short8*)&Bs[cur][(wc + 16 + lr)*64 + kk + kh];
            acc[0][0] = __builtin_amdgcn_mfma_f32_16x16x32_bf16(a0, b0, acc[0][0], 0, 0, 0);
            acc[0][1] = __builtin_amdgcn_mfma_f32_16x16x32_bf16(a0, b1, acc[0][1], 0, 0, 0);
            acc[1][0] = __builtin_amdgcn_mfma_f32_16x16x32_bf16(a1, b0, acc[1][0], 0, 0, 0);
            acc[1][1] = __builtin_amdgcn_mfma_f32_16x16x32_bf16(a1, b1, acc[1][1], 0, 0, 0);
        }
        __syncthreads();
    }
    #pragma unroll
    for (int i = 0; i < 2; ++i)
    #pragma unroll
    for (int j = 0; j < 2; ++j)
    #pragma unroll
    for (int q = 0; q < 4; ++q) {
        int row = row0 + wr + i*16 + (lane >> 4)*4 + q;
        int col = col0 + wc + j*16 + (lane & 15);
        float v = acc[i][j][q] + ((col < biasN) ? bias[col] : 0.f);
        C[(size_t)row * ldc + col] = f2bf(lrelu(v));
    }
}

// ========== tail: R3 = lrelu(R2 @ oW3t^T + ob3) (f32, LDS) ; out = R3 @ sW + sb =====
// 64 blocks x 32 rows. Tile 32 x 128 (full N), K=256 staged once.
__global__ __launch_bounds__(256) void tail_kernel(const ushort* __restrict__ R2,
                                                   const ushort* __restrict__ oW3t,
                                                   const float* __restrict__ ob3,
                                                   const float* __restrict__ sW,
                                                   const float* __restrict__ sb,
                                                   float* __restrict__ out) {
    __shared__ __align__(16) ushort As[32 * 256];    // 16KB
    __shared__ __align__(16) ushort Bs[128 * 256];   // 64KB
    __shared__ float R3s[32][128];                   // 16KB
    __shared__ float sWs[127 * 9];
    __shared__ float sbs[9];
    const int row0 = blockIdx.x * 32;
    const int tid = threadIdx.x, lane = tid & 63, wave = tid >> 6;
    const int lr = lane & 15, kh = (lane >> 4) * 8;
    const int crow = lane >> 5, ccol = (lane & 31) * 8;

    // stage A (16 chunks) + B (64 chunks)
    #pragma unroll
    for (int c = 0; c < 4; ++c) {
        int q = wave * 4 + c;
        gload16(R2 + (size_t)(row0 + q*2 + crow) * 256 + ccol, (void*)&As[q * 512]);
    }
    #pragma unroll
    for (int c = 0; c < 16; ++c) {
        int q = wave * 16 + c;
        gload16(oW3t + (size_t)(q*2 + crow) * 256 + ccol, (void*)&Bs[q * 512]);
    }
    for (int i = tid; i < 127 * 9; i += 256) sWs[i] = sW[i];
    if (tid < 9) sbs[tid] = sb[tid];
    __syncthreads();

    f32x4 acc[2][2] = {};
    #pragma unroll
    for (int kk = 0; kk < 256; kk += 32) {
        short8 a0 = *(const short8*)&As[(lr)*256 + kk + kh];
        short8 a1 = *(const short8*)&As[(16 + lr)*256 + kk + kh];
        short8 b0 = *(const short8*)&Bs[(wave*32 + lr)*256 + kk + kh];
        short8 b1 = *(const short8*)&Bs[(wave*32 + 16 + lr)*256 + kk + kh];
        acc[0][0] = __builtin_amdgcn_mfma_f32_16x16x32_bf16(a0, b0, acc[0][0], 0, 0, 0);
        acc[0][1] = __builtin_amdgcn_mfma_f32_16x16x32_bf16(a0, b1, acc[0][1], 0, 0, 0);
        acc[1][0] = __builtin_amdgcn_mfma_f32_16x16x32_bf16(a1, b0, acc[1][0], 0, 0, 0);
        acc[1][1] = __builtin_amdgcn_mfma_f32_16x16x32_bf16(a1, b1, acc[1][1], 0, 0, 0);
    }
    #pragma unroll
    for (int g = 0; g < 2; ++g)
    #pragma unroll
    for (int j = 0; j < 2; ++j)
    #pragma unroll
    for (int q = 0; q < 4; ++q) {
        int row = g*16 + (lane >> 4)*4 + q;
        int col = wave*32 + j*16 + (lane & 15);
        float bias = (col < 127) ? ob3[col] : 0.f;
        R3s[row][col] = lrelu(acc[g][j][q] + bias);
    }
    __syncthreads();
    for (int idx = tid; idx < 32 * 9; idx += 256) {
        int row = idx / 9, a = idx - row * 9;
        float s = sbs[a];
        for (int n = 0; n < 127; ++n) s += R3s[row][n] * sWs[n * 9 + a];
        out[(size_t)(row0 + row) * 9 + a] = s;
    }
}

extern "C" void kernel_launch(void* const* d_in, const int* in_sizes, int n_in,
                              void* d_out, int out_size, void* d_ws, size_t ws_size,
                              hipStream_t stream) {
    const int*   x    = (const int*)  d_in[0];
    const float* emb  = (const float*)d_in[1];
    const float* hW1  = (const float*)d_in[2];
    const float* hb1  = (const float*)d_in[3];
    const float* hW2  = (const float*)d_in[4];
    const float* hb2  = (const float*)d_in[5];
    const float* bW1  = (const float*)d_in[6];
    const float* bb1  = (const float*)d_in[7];
    const float* bW2  = (const float*)d_in[8];
    const float* bb2  = (const float*)d_in[9];
    const float* oW1  = (const float*)d_in[10];
    const float* ob1  = (const float*)d_in[11];
    const float* oW2  = (const float*)d_in[12];
    const float* ob2  = (const float*)d_in[13];
    const float* oW3  = (const float*)d_in[14];
    const float* ob3  = (const float*)d_in[15];
    const float* sW   = (const float*)d_in[16];
    const float* sb   = (const float*)d_in[17];

    char* ws = (char*)d_ws;
    constexpr size_t OFF_T    = 0;                     // 5*53*512 f32  = 542,720
    constexpr size_t OFF_HW2T = 542720;                // 128x512 bf16  = 131,072
    constexpr size_t OFF_BW2T = OFF_HW2T + 131072;
    constexpr size_t OFF_OW2T = OFF_BW2T + 131072;     // 256x512 bf16  = 262,144
    constexpr size_t OFF_OW3T = OFF_OW2T + 262144;     // 128x256 bf16  = 65,536
    constexpr size_t OFF_WCT  = OFF_OW3T + 65536;      // 512x2048 bf16 = 2,097,152
    constexpr size_t OFF_CID  = OFF_WCT + 2097152;     // 2048x9 i32    = 73,728
    constexpr size_t OFF_X    = OFF_CID + 73728;       // 2048x2048 bf16= 8,388,608
    constexpr size_t OFF_R1   = OFF_X + 8388608;       // 2048x512 bf16 = 2,097,152
    constexpr size_t OFF_R2   = OFF_R1 + 2097152;      // 2048x256 bf16 = 1,048,576

    float*  T    = (float*)(ws + OFF_T);
    ushort* hW2t = (ushort*)(ws + OFF_HW2T);
    ushort* bW2t = (ushort*)(ws + OFF_BW2T);
    ushort* oW2t = (ushort*)(ws + OFF_OW2T);
    ushort* oW3t = (ushort*)(ws + OFF_OW3T);
    ushort* Wct  = (ushort*)(ws + OFF_WCT);
    int*    cid  = (int*)(ws + OFF_CID);
    ushort* X    = (ushort*)(ws + OFF_X);
    ushort* R1   = (ushort*)(ws + OFF_R1);
    ushort* R2   = (ushort*)(ws + OFF_R2);

    prep_all<<<PB_END, 512, 0, stream>>>(x, emb, hW1, hb1, hW2, bW1, bb1, bW2,
                                         oW1, oW2, oW3,
                                         T, hW2t, bW2t, oW2t, oW3t, Wct, cid);
    l2_fused<<<512, 256, 0, stream>>>(cid, T, hW2t, bW2t, hb2, bb2, X);
    gemm64<<<dim3(32, 8), 256, 0, stream>>>(X, Wct, ob1, 512, R1, 2048, 512);
    gemm64<<<dim3(32, 4), 256, 0, stream>>>(R1, oW2t, ob2, 256, R2, 512, 256);
    tail_kernel<<<64, 256, 0, stream>>>(R2, oW3t, ob3, sW, sb, (float*)d_out);
}

// Round 4
// 74.313 us; speedup vs baseline: 2.5433x; 1.1232x over previous
//
#include <hip/hip_runtime.h>

typedef __attribute__((ext_vector_type(8))) short short8;
typedef __attribute__((ext_vector_type(4))) float f32x4;

__device__ inline float lrelu(float v){ return v > 0.f ? v : 0.01f*v; }
__device__ inline ushort f2bf(float f){
    unsigned u = __float_as_uint(f);
    return (ushort)((u + 0x7fffu + ((u >> 16) & 1u)) >> 16);
}

__device__ __forceinline__ void gload16(const void* gp, void* lp) {
    __builtin_amdgcn_global_load_lds(
        (const __attribute__((address_space(1))) unsigned int*)gp,
        (__attribute__((address_space(3))) unsigned int*)lp,
        16, 0, 0);
}

#define M_ROWS 2048

// ======================= launch 1: prep needed by l2_fused =======================
//   [0,265)    prep_T : T[slot][card][512] = emb[card] @ Wslice (+bias folded)
//   [265,393)  hW2t   : transpose->bf16 128x512
//   [393,521)  bW2t   : transpose->bf16 128x512
//   [521,525)  cards  : parse+sort -> cid
#define P1_T    0
#define P1_HW2  265
#define P1_BW2  393
#define P1_CARD 521
#define P1_END  525

__device__ void d_transpose512(const float* __restrict__ in, ushort* __restrict__ out,
                               int K, int Nin, int Nout, int b, int tid) {
    int idx = b * 512 + tid;
    if (idx >= Nout * K) return;
    int n = idx / K, k = idx - n * K;
    float v = (n < Nin) ? in[(size_t)k * Nin + n] : 0.f;
    out[idx] = f2bf(v);
}

__global__ __launch_bounds__(512) void prep1(const int* __restrict__ x,
                                             const float* __restrict__ emb,
                                             const float* __restrict__ hW1,
                                             const float* __restrict__ hb1,
                                             const float* __restrict__ hW2,
                                             const float* __restrict__ bW1,
                                             const float* __restrict__ bb1,
                                             const float* __restrict__ bW2,
                                             float* __restrict__ T,
                                             ushort* __restrict__ hW2t,
                                             ushort* __restrict__ bW2t,
                                             int* __restrict__ cid) {
    const int bid = blockIdx.x, tid = threadIdx.x;
    if (bid < P1_HW2) {
        int b = bid;                 // slot*53 + card
        int slot = b / 53, card = b - slot * 53;
        const float* W = (slot < 2) ? (hW1 + slot * 64 * 512) : (bW1 + (slot - 2) * 64 * 512);
        const float* e = emb + card * 64;
        float acc = (slot == 1) ? hb1[tid] : ((slot == 4) ? bb1[tid] : 0.f);
        #pragma unroll 8
        for (int k = 0; k < 64; ++k) acc += e[k] * W[k * 512 + tid];
        T[(size_t)b * 512 + tid] = acc;
    } else if (bid < P1_BW2) {
        d_transpose512(hW2, hW2t, 512, 128, 128, bid - P1_HW2, tid);
    } else if (bid < P1_CARD) {
        d_transpose512(bW2, bW2t, 512, 128, 128, bid - P1_BW2, tid);
    } else {
        int m = (bid - P1_CARD) * 512 + tid;
        if (m >= M_ROWS) return;
        int kh[4], kb[5];
        #pragma unroll
        for (int i = 0; i < 4; ++i) { int r = x[m*18 + 2*i], s = x[m*18 + 2*i + 1]; kh[i] = r*8 + s; }
        #pragma unroll
        for (int i = 0; i < 5; ++i) { int r = x[m*18 + 8 + 2*i], s = x[m*18 + 9 + 2*i]; kb[i] = r*8 + s; }
        #pragma unroll
        for (int i = 1; i < 4; ++i) { int v = kh[i], j = i-1; while (j >= 0 && kh[j] > v) { kh[j+1]=kh[j]; --j; } kh[j+1]=v; }
        #pragma unroll
        for (int i = 1; i < 5; ++i) { int v = kb[i], j = i-1; while (j >= 0 && kb[j] > v) { kb[j+1]=kb[j]; --j; } kb[j+1]=v; }
        #pragma unroll
        for (int i = 0; i < 4; ++i) { int r = kh[i] >> 3, s = kh[i] & 7; cid[m*9 + i] = (r - 1) * s; }
        #pragma unroll
        for (int i = 0; i < 5; ++i) { int r = kb[i] >> 3, s = kb[i] & 7; cid[m*9 + 4 + i] = (r - 1) * s; }
    }
}

// ===== launch 2 (mega): l2_fused + all prep consumed only by later launches =====
//   [0,512)       l2_fused : fused layer-1 build + layer-2 GEMM -> X
//   [512,768)     prep_Wct : Wct[512][2048] block-sum-transpose of oW1
//   [768,1280)    oW2t     : transpose->bf16 256x512
//   [1280,1408)   oW3t     : transpose->bf16 128x256 (row 127 zero-pad)
#define M_L2   0
#define M_WCT  512
#define M_OW2  768
#define M_OW3  1280
#define M_END  1408

__global__ __launch_bounds__(256) void mega(const int* __restrict__ cid,
                                            const float* __restrict__ T,
                                            const ushort* __restrict__ hW2t,
                                            const ushort* __restrict__ bW2t,
                                            const float* __restrict__ hb2,
                                            const float* __restrict__ bb2,
                                            const float* __restrict__ oW1,
                                            const float* __restrict__ oW2,
                                            const float* __restrict__ oW3,
                                            ushort* __restrict__ X,
                                            ushort* __restrict__ Wct,
                                            ushort* __restrict__ oW2t,
                                            ushort* __restrict__ oW3t) {
    __shared__ __align__(16) char smem[51200];
    const int bid = blockIdx.x, tid = threadIdx.x;

    if (bid < M_WCT) {
        // ---------------- l2_fused ----------------
        // As: padded [2][64][72] (reg-built, 2-way-free reads). Bs: linear [2][128*64],
        // global_load_lds dest, source pre-swizzled chunk^=(row&7), reads XOR the same.
        ushort (*As)[64][72] = (ushort(*)[64][72])smem;              // 18432 B
        ushort (*Bs)[128*64] = (ushort(*)[128*64])(smem + 18432);    // 32768 B
        const bool hero = bid < 192;
        const int row0 = hero ? bid * 64 : (bid - 192) * 64;
        const ushort* Bt = hero ? hW2t : bW2t;
        const float* bias = hero ? hb2 : bb2;
        const int lane = tid & 63, wave = tid >> 6;
        const int lr = lane & 15, khh = (lane >> 4) * 8;
        const int sb_off = (((lane & 7) ^ (lane >> 3)) << 3);        // swizzled src elem off

        const int br = tid >> 2, bc = (tid & 3) * 16;
        const int grow = row0 + br;
        const float *t0, *t1, *t2;
        if (hero) {
            const int HP0[6] = {0,0,0,1,1,2}, HP1[6] = {1,2,3,2,3,3};
            int m = grow / 6, p = grow - m * 6;
            t0 = T + (size_t)(0*53 + cid[m*9 + HP0[p]]) * 512;
            t1 = T + (size_t)(1*53 + cid[m*9 + HP1[p]]) * 512;
            t2 = T;   // slot0 card0 == all zeros
        } else {
            const int BT0[10] = {4,4,4,4,4,4,5,5,5,6};
            const int BT1[10] = {5,5,5,6,6,7,6,6,7,7};
            const int BT2[10] = {6,7,8,7,8,8,7,8,8,8};
            int m = grow / 10, t = grow - m * 10;
            t0 = T + (size_t)(2*53 + cid[m*9 + BT0[t]]) * 512;
            t1 = T + (size_t)(3*53 + cid[m*9 + BT1[t]]) * 512;
            t2 = T + (size_t)(4*53 + cid[m*9 + BT2[t]]) * 512;
        }

        auto stageB = [&](int buf, int k0) {
            #pragma unroll
            for (int c = 0; c < 4; ++c) {
                int q = wave * 4 + c;
                int r = q * 8 + (lane >> 3);
                gload16(Bt + (size_t)r * 512 + k0 + sb_off, (void*)&(*Bs)[buf == 0 ? 0 : 128*64]);
                (void)r;
                // NOTE: dest must be wave-uniform; recompute properly below
            }
        };
        (void)stageB;
        // (lambda above unused; explicit staging below keeps dest arithmetic clear)

        auto stageB2 = [&](int buf, int k0) {
            #pragma unroll
            for (int c = 0; c < 4; ++c) {
                int q = wave * 4 + c;
                int r = q * 8 + (lane >> 3);
                gload16(Bt + (size_t)r * 512 + k0 + sb_off, (void*)&Bs[buf][q * 512]);
            }
        };
        auto buildA = [&](int buf, int k0) {
            #pragma unroll
            for (int h = 0; h < 2; ++h) {
                int kc = bc + h * 8;
                const f32x4* q0 = (const f32x4*)(t0 + k0 + kc);
                const f32x4* q1 = (const f32x4*)(t1 + k0 + kc);
                const f32x4* q2 = (const f32x4*)(t2 + k0 + kc);
                f32x4 u0 = q0[0], u1 = q1[0], u2 = q2[0];
                f32x4 v0 = q0[1], v1 = q1[1], v2 = q2[1];
                short8 pk;
                #pragma unroll
                for (int j = 0; j < 4; ++j) pk[j] = (short)f2bf(lrelu(u0[j] + u1[j] + u2[j]));
                #pragma unroll
                for (int j = 0; j < 4; ++j) pk[4+j] = (short)f2bf(lrelu(v0[j] + v1[j] + v2[j]));
                *(short8*)&As[buf][br][kc] = pk;
            }
        };

        f32x4 acc[4][2] = {};
        stageB2(0, 0); buildA(0, 0);
        __syncthreads();
        for (int t = 0; t < 8; ++t) {
            int cur = t & 1;
            if (t < 7) { stageB2(cur ^ 1, (t + 1) * 64); buildA(cur ^ 1, (t + 1) * 64); }
            #pragma unroll
            for (int kk2 = 0; kk2 < 2; ++kk2) {
                int kk = kk2 * 32;
                int g  = kk2 * 4 + (lane >> 4);          // B chunk index 0..7
                int eo = ((g ^ (lr & 7)) << 3);          // swizzled read elem offset
                short8 a[4], b[2];
                #pragma unroll
                for (int gg = 0; gg < 4; ++gg) a[gg] = *(const short8*)&As[cur][gg*16 + lr][kk + khh];
                #pragma unroll
                for (int j = 0; j < 2; ++j) b[j] = *(const short8*)&Bs[cur][(wave*32 + j*16 + lr)*64 + eo];
                #pragma unroll
                for (int gg = 0; gg < 4; ++gg)
                    #pragma unroll
                    for (int j = 0; j < 2; ++j)
                        acc[gg][j] = __builtin_amdgcn_mfma_f32_16x16x32_bf16(a[gg], b[j], acc[gg][j], 0, 0, 0);
            }
            __syncthreads();
        }
        #pragma unroll
        for (int g = 0; g < 4; ++g)
        #pragma unroll
        for (int j = 0; j < 2; ++j)
        #pragma unroll
        for (int q = 0; q < 4; ++q) {
            int row = row0 + g*16 + (lane >> 4)*4 + q;
            int col = wave*32 + j*16 + (lane & 15);
            float v = lrelu(acc[g][j][q] + bias[col]);
            size_t off;
            if (hero) { int m = row / 6,  p = row - m*6;  off = (size_t)m*2048 + p*128 + col; }
            else      { int m = row / 10, p = row - m*10; off = (size_t)m*2048 + 768 + p*128 + col; }
            X[off] = f2bf(v);
        }
    } else if (bid < M_OW2) {
        // ---------------- prep_Wct ----------------
        float (*tile)[65] = (float(*)[65])smem;
        int b = bid - M_WCT;
        int kb = b & 31, nb = b >> 5;
        int nl = tid & 63;
        for (int kl = tid >> 6; kl < 64; kl += 4) {
            int col = kb * 64 + kl;
            int p = col >> 7, r = col & 127;
            int n = nb * 64 + nl;
            float s = 0.f;
            if (p < 6) {
                #pragma unroll
                for (int j = 0; j < 10; ++j) s += oW1[(size_t)((p * 10 + j) * 256 + r) * 512 + n];
            } else {
                int t = p - 6;
                #pragma unroll
                for (int i = 0; i < 6; ++i) s += oW1[(size_t)((i * 10 + t) * 256 + 128 + r) * 512 + n];
            }
            tile[kl][nl] = s;
        }
        __syncthreads();
        for (int nl2 = tid >> 6; nl2 < 64; nl2 += 4) {
            int kl2 = tid & 63;
            Wct[(size_t)(nb * 64 + nl2) * 2048 + kb * 64 + kl2] = f2bf(tile[kl2][nl2]);
        }
    } else if (bid < M_OW3) {
        int idx = (bid - M_OW2) * 256 + tid;      // 256x512
        int n = idx / 512, k = idx - n * 512;
        oW2t[idx] = f2bf(oW2[(size_t)k * 256 + n]);
    } else {
        int idx = (bid - M_OW3) * 256 + tid;      // 128x256
        int n = idx / 256, k = idx - n * 256;
        float v = (n < 127) ? oW3[(size_t)k * 127 + n] : 0.f;
        oW3t[idx] = f2bf(v);
    }
}

// ===== generic MFMA GEMM, dbuf + swizzled LDS: C = lrelu(A @ Bt^T + bias) =====
__global__ __launch_bounds__(256) void gemm64(const ushort* __restrict__ A,
                                              const ushort* __restrict__ Bt,
                                              const float* __restrict__ bias, int biasN,
                                              ushort* __restrict__ C,
                                              int K_, int ldc) {
    __shared__ __align__(16) ushort As[2][64 * 64];
    __shared__ __align__(16) ushort Bs[2][64 * 64];
    const int row0 = blockIdx.x * 64, col0 = blockIdx.y * 64;
    const int tid = threadIdx.x, lane = tid & 63, wave = tid >> 6;
    const int wr = (wave >> 1) * 32, wc = (wave & 1) * 32;
    const int lr = lane & 15;
    const int srow = lane >> 3;
    const int scw = (((lane & 7) ^ srow) << 3);   // swizzled source elem offset

    auto stage = [&](int buf, int k0) {
        #pragma unroll
        for (int c = 0; c < 2; ++c) {
            int q = wave * 2 + c;
            int r = q * 8 + srow;
            gload16(A  + (size_t)(row0 + r) * K_ + k0 + scw, (void*)&As[buf][q * 512]);
            gload16(Bt + (size_t)(col0 + r) * K_ + k0 + scw, (void*)&Bs[buf][q * 512]);
        }
    };

    f32x4 acc[2][2] = {};
    stage(0, 0);
    __syncthreads();
    const int nt = K_ >> 6;
    for (int t = 0; t < nt; ++t) {
        int cur = t & 1;
        if (t + 1 < nt) stage(cur ^ 1, (t + 1) * 64);
        #pragma unroll
        for (int kk2 = 0; kk2 < 2; ++kk2) {
            int g  = kk2 * 4 + (lane >> 4);
            int eo = ((g ^ (lr & 7)) << 3);
            short8 a0 = *(const short8*)&As[cur][(wr + lr)*64 + eo];
            short8 a1 = *(const short8*)&As[cur][(wr + 16 + lr)*64 + eo];
            short8 b0 = *(const short8*)&Bs[cur][(wc + lr)*64 + eo];
            short8 b1 = *(const short8*)&Bs[cur][(wc + 16 + lr)*64 + eo];
            acc[0][0] = __builtin_amdgcn_mfma_f32_16x16x32_bf16(a0, b0, acc[0][0], 0, 0, 0);
            acc[0][1] = __builtin_amdgcn_mfma_f32_16x16x32_bf16(a0, b1, acc[0][1], 0, 0, 0);
            acc[1][0] = __builtin_amdgcn_mfma_f32_16x16x32_bf16(a1, b0, acc[1][0], 0, 0, 0);
            acc[1][1] = __builtin_amdgcn_mfma_f32_16x16x32_bf16(a1, b1, acc[1][1], 0, 0, 0);
        }
        __syncthreads();
    }
    #pragma unroll
    for (int i = 0; i < 2; ++i)
    #pragma unroll
    for (int j = 0; j < 2; ++j)
    #pragma unroll
    for (int q = 0; q < 4; ++q) {
        int row = row0 + wr + i*16 + (lane >> 4)*4 + q;
        int col = col0 + wc + j*16 + (lane & 15);
        float v = acc[i][j][q] + ((col < biasN) ? bias[col] : 0.f);
        C[(size_t)row * ldc + col] = f2bf(lrelu(v));
    }
}

// ===== tail: R3 = lrelu(R2 @ oW3t^T + ob3) (f32, LDS) ; out = R3 @ sW + sb =====
__global__ __launch_bounds__(256) void tail_kernel(const ushort* __restrict__ R2,
                                                   const ushort* __restrict__ oW3t,
                                                   const float* __restrict__ ob3,
                                                   const float* __restrict__ sW,
                                                   const float* __restrict__ sb,
                                                   float* __restrict__ out) {
    __shared__ __align__(16) ushort As[32 * 256];    // 16KB, rows of 512B (32 chunks)
    __shared__ __align__(16) ushort Bs[128 * 256];   // 64KB
    __shared__ float R3s[32][132];                   // padded
    __shared__ float sWs[127 * 9];
    __shared__ float sbs[9];
    const int row0 = blockIdx.x * 32;
    const int tid = threadIdx.x, lane = tid & 63, wave = tid >> 6;
    const int lr = lane & 15;
    const int crow = lane >> 5;

    #pragma unroll
    for (int c = 0; c < 4; ++c) {
        int q = wave * 4 + c;
        int r = q * 2 + crow;
        gload16(R2 + (size_t)(row0 + r) * 256 + (((lane & 31) ^ (r & 7)) << 3), (void*)&As[q * 512]);
    }
    #pragma unroll
    for (int c = 0; c < 16; ++c) {
        int q = wave * 16 + c;
        int r = q * 2 + crow;
        gload16(oW3t + (size_t)r * 256 + (((lane & 31) ^ (r & 7)) << 3), (void*)&Bs[q * 512]);
    }
    for (int i = tid; i < 127 * 9; i += 256) sWs[i] = sW[i];
    if (tid < 9) sbs[tid] = sb[tid];
    __syncthreads();

    f32x4 acc[2][2] = {};
    #pragma unroll
    for (int kk2 = 0; kk2 < 8; ++kk2) {
        int g  = kk2 * 4 + (lane >> 4);          // chunk 0..31
        int eo = ((g ^ (lr & 7)) << 3);
        short8 a0 = *(const short8*)&As[(lr)*256 + eo];
        short8 a1 = *(const short8*)&As[(16 + lr)*256 + eo];
        short8 b0 = *(const short8*)&Bs[(wave*32 + lr)*256 + eo];
        short8 b1 = *(const short8*)&Bs[(wave*32 + 16 + lr)*256 + eo];
        acc[0][0] = __builtin_amdgcn_mfma_f32_16x16x32_bf16(a0, b0, acc[0][0], 0, 0, 0);
        acc[0][1] = __builtin_amdgcn_mfma_f32_16x16x32_bf16(a0, b1, acc[0][1], 0, 0, 0);
        acc[1][0] = __builtin_amdgcn_mfma_f32_16x16x32_bf16(a1, b0, acc[1][0], 0, 0, 0);
        acc[1][1] = __builtin_amdgcn_mfma_f32_16x16x32_bf16(a1, b1, acc[1][1], 0, 0, 0);
    }
    #pragma unroll
    for (int g = 0; g < 2; ++g)
    #pragma unroll
    for (int j = 0; j < 2; ++j)
    #pragma unroll
    for (int q = 0; q < 4; ++q) {
        int row = g*16 + (lane >> 4)*4 + q;
        int col = wave*32 + j*16 + (lane & 15);
        float bias = (col < 127) ? ob3[col] : 0.f;
        R3s[row][col] = lrelu(acc[g][j][q] + bias);
    }
    __syncthreads();
    for (int idx = tid; idx < 32 * 9; idx += 256) {
        int row = idx / 9, a = idx - row * 9;
        float s = sbs[a];
        for (int n = 0; n < 127; ++n) s += R3s[row][n] * sWs[n * 9 + a];
        out[(size_t)(row0 + row) * 9 + a] = s;
    }
}

extern "C" void kernel_launch(void* const* d_in, const int* in_sizes, int n_in,
                              void* d_out, int out_size, void* d_ws, size_t ws_size,
                              hipStream_t stream) {
    const int*   x    = (const int*)  d_in[0];
    const float* emb  = (const float*)d_in[1];
    const float* hW1  = (const float*)d_in[2];
    const float* hb1  = (const float*)d_in[3];
    const float* hW2  = (const float*)d_in[4];
    const float* hb2  = (const float*)d_in[5];
    const float* bW1  = (const float*)d_in[6];
    const float* bb1  = (const float*)d_in[7];
    const float* bW2  = (const float*)d_in[8];
    const float* bb2  = (const float*)d_in[9];
    const float* oW1  = (const float*)d_in[10];
    const float* ob1  = (const float*)d_in[11];
    const float* oW2  = (const float*)d_in[12];
    const float* ob2  = (const float*)d_in[13];
    const float* oW3  = (const float*)d_in[14];
    const float* ob3  = (const float*)d_in[15];
    const float* sW   = (const float*)d_in[16];
    const float* sb   = (const float*)d_in[17];

    char* ws = (char*)d_ws;
    constexpr size_t OFF_T    = 0;                     // 5*53*512 f32  = 542,720
    constexpr size_t OFF_HW2T = 542720;                // 128x512 bf16  = 131,072
    constexpr size_t OFF_BW2T = OFF_HW2T + 131072;
    constexpr size_t OFF_OW2T = OFF_BW2T + 131072;     // 256x512 bf16  = 262,144
    constexpr size_t OFF_OW3T = OFF_OW2T + 262144;     // 128x256 bf16  = 65,536
    constexpr size_t OFF_WCT  = OFF_OW3T + 65536;      // 512x2048 bf16 = 2,097,152
    constexpr size_t OFF_CID  = OFF_WCT + 2097152;     // 2048x9 i32    = 73,728
    constexpr size_t OFF_X    = OFF_CID + 73728;       // 2048x2048 bf16= 8,388,608
    constexpr size_t OFF_R1   = OFF_X + 8388608;       // 2048x512 bf16 = 2,097,152
    constexpr size_t OFF_R2   = OFF_R1 + 2097152;      // 2048x256 bf16 = 1,048,576

    float*  T    = (float*)(ws + OFF_T);
    ushort* hW2t = (ushort*)(ws + OFF_HW2T);
    ushort* bW2t = (ushort*)(ws + OFF_BW2T);
    ushort* oW2t = (ushort*)(ws + OFF_OW2T);
    ushort* oW3t = (ushort*)(ws + OFF_OW3T);
    ushort* Wct  = (ushort*)(ws + OFF_WCT);
    int*    cid  = (int*)(ws + OFF_CID);
    ushort* X    = (ushort*)(ws + OFF_X);
    ushort* R1   = (ushort*)(ws + OFF_R1);
    ushort* R2   = (ushort*)(ws + OFF_R2);

    prep1<<<P1_END, 512, 0, stream>>>(x, emb, hW1, hb1, hW2, bW1, bb1, bW2,
                                      T, hW2t, bW2t, cid);
    mega<<<M_END, 256, 0, stream>>>(cid, T, hW2t, bW2t, hb2, bb2,
                                    oW1, oW2, oW3, X, Wct, oW2t, oW3t);
    gemm64<<<dim3(32, 8), 256, 0, stream>>>(X, Wct, ob1, 512, R1, 2048, 512);
    gemm64<<<dim3(32, 4), 256, 0, stream>>>(R1, oW2t, ob2, 256, R2, 512, 256);
    tail_kernel<<<64, 256, 0, stream>>>(R2, oW3t, ob3, sW, sb, (float*)d_out);
}

// Round 5
// 60.530 us; speedup vs baseline: 3.1224x; 1.2277x over previous
//
#include <hip/hip_runtime.h>

typedef _Float16 f16;
typedef __attribute__((ext_vector_type(8))) _Float16 f16x8;
typedef __attribute__((ext_vector_type(4))) float f32x4;

__device__ inline float lrelu(float v){ return v > 0.f ? v : 0.01f*v; }
__device__ inline f16x8 lrelu8(f16x8 v){
    f16x8 z = {};
    f16x8 mx = __builtin_elementwise_max(v, z);
    f16x8 mn = __builtin_elementwise_min(v, z);
    return mx + mn * (f16)0.01f;
}

__device__ __forceinline__ void gload16(const void* gp, void* lp) {
    __builtin_amdgcn_global_load_lds(
        (const __attribute__((address_space(1))) unsigned int*)gp,
        (__attribute__((address_space(3))) unsigned int*)lp,
        16, 0, 0);
}

#define M_ROWS 2048

// ======================= launch 1: all pure-input prep =======================
//   [0,265)    prep_T : T[slot][card][512] = emb[card] @ Wslice (+bias folded), f16
//   [265,393)  hW2t   : transpose->f16 128x512
//   [393,521)  bW2t   : transpose->f16 128x512
//   [521,777)  oW2t   : transpose->f16 256x512
//   [777,841)  oW3t   : transpose->f16 128x256 (row 127 zero-pad)
//   [841,845)  cards  : parse+sort -> cid
#define P1_T    0
#define P1_HW2  265
#define P1_BW2  393
#define P1_OW2  521
#define P1_OW3  777
#define P1_CARD 841
#define P1_END  845

__device__ void d_transpose512(const float* __restrict__ in, f16* __restrict__ out,
                               int K, int Nin, int Nout, int b, int tid) {
    int idx = b * 512 + tid;
    if (idx >= Nout * K) return;
    int n = idx / K, k = idx - n * K;
    float v = (n < Nin) ? in[(size_t)k * Nin + n] : 0.f;
    out[idx] = (f16)v;
}

__global__ __launch_bounds__(512) void prep1(const int* __restrict__ x,
                                             const float* __restrict__ emb,
                                             const float* __restrict__ hW1,
                                             const float* __restrict__ hb1,
                                             const float* __restrict__ hW2,
                                             const float* __restrict__ bW1,
                                             const float* __restrict__ bb1,
                                             const float* __restrict__ bW2,
                                             const float* __restrict__ oW2,
                                             const float* __restrict__ oW3,
                                             f16* __restrict__ T,
                                             f16* __restrict__ hW2t,
                                             f16* __restrict__ bW2t,
                                             f16* __restrict__ oW2t,
                                             f16* __restrict__ oW3t,
                                             int* __restrict__ cid) {
    const int bid = blockIdx.x, tid = threadIdx.x;
    if (bid < P1_HW2) {
        int b = bid;                 // slot*53 + card
        int slot = b / 53, card = b - slot * 53;
        const float* W = (slot < 2) ? (hW1 + slot * 64 * 512) : (bW1 + (slot - 2) * 64 * 512);
        const float* e = emb + card * 64;
        float acc = (slot == 1) ? hb1[tid] : ((slot == 4) ? bb1[tid] : 0.f);
        #pragma unroll 8
        for (int k = 0; k < 64; ++k) acc += e[k] * W[k * 512 + tid];
        T[(size_t)b * 512 + tid] = (f16)acc;
    } else if (bid < P1_BW2) {
        d_transpose512(hW2, hW2t, 512, 128, 128, bid - P1_HW2, tid);
    } else if (bid < P1_OW2) {
        d_transpose512(bW2, bW2t, 512, 128, 128, bid - P1_BW2, tid);
    } else if (bid < P1_OW3) {
        d_transpose512(oW2, oW2t, 512, 256, 256, bid - P1_OW2, tid);
    } else if (bid < P1_CARD) {
        d_transpose512(oW3, oW3t, 256, 127, 128, bid - P1_OW3, tid);
    } else {
        int m = (bid - P1_CARD) * 512 + tid;
        if (m >= M_ROWS) return;
        int kh[4], kb[5];
        #pragma unroll
        for (int i = 0; i < 4; ++i) { int r = x[m*18 + 2*i], s = x[m*18 + 2*i + 1]; kh[i] = r*8 + s; }
        #pragma unroll
        for (int i = 0; i < 5; ++i) { int r = x[m*18 + 8 + 2*i], s = x[m*18 + 9 + 2*i]; kb[i] = r*8 + s; }
        #pragma unroll
        for (int i = 1; i < 4; ++i) { int v = kh[i], j = i-1; while (j >= 0 && kh[j] > v) { kh[j+1]=kh[j]; --j; } kh[j+1]=v; }
        #pragma unroll
        for (int i = 1; i < 5; ++i) { int v = kb[i], j = i-1; while (j >= 0 && kb[j] > v) { kb[j+1]=kb[j]; --j; } kb[j+1]=v; }
        #pragma unroll
        for (int i = 0; i < 4; ++i) { int r = kh[i] >> 3, s = kh[i] & 7; cid[m*9 + i] = (r - 1) * s; }
        #pragma unroll
        for (int i = 0; i < 5; ++i) { int r = kb[i] >> 3, s = kb[i] & 7; cid[m*9 + 4 + i] = (r - 1) * s; }
    }
}

// ===== launch 2 (mega): Wct prep (first, starts HBM read) + l2_fused =====
//   [0,256)     prep_Wct : Wct[512][2048] f16 block-sum-transpose of oW1
//   [256,768)   l2_fused : fused layer-1 build + layer-2 GEMM -> X (f16)
#define MG_L2  256
#define MG_END 768

__global__ __launch_bounds__(512) void mega(const int* __restrict__ cid,
                                            const f16* __restrict__ T,
                                            const f16* __restrict__ hW2t,
                                            const f16* __restrict__ bW2t,
                                            const float* __restrict__ hb2,
                                            const float* __restrict__ bb2,
                                            const float* __restrict__ oW1,
                                            f16* __restrict__ X,
                                            f16* __restrict__ Wct) {
    __shared__ __align__(16) char smem[51200];
    const int bid = blockIdx.x, tid = threadIdx.x;

    if (bid < MG_L2) {
        // ---------------- prep_Wct ----------------
        float (*tile)[65] = (float(*)[65])smem;
        int kb = bid & 31, nb = bid >> 5;
        int nl = tid & 63;
        for (int kl = tid >> 6; kl < 64; kl += 8) {
            int col = kb * 64 + kl;
            int p = col >> 7, r = col & 127;
            int n = nb * 64 + nl;
            float s = 0.f;
            if (p < 6) {
                #pragma unroll
                for (int j = 0; j < 10; ++j) s += oW1[(size_t)((p * 10 + j) * 256 + r) * 512 + n];
            } else {
                int t = p - 6;
                #pragma unroll
                for (int i = 0; i < 6; ++i) s += oW1[(size_t)((i * 10 + t) * 256 + 128 + r) * 512 + n];
            }
            tile[kl][nl] = s;
        }
        __syncthreads();
        for (int nl2 = tid >> 6; nl2 < 64; nl2 += 8) {
            int kl2 = tid & 63;
            Wct[(size_t)(nb * 64 + nl2) * 2048 + kb * 64 + kl2] = (f16)tile[kl2][nl2];
        }
        return;
    }

    // ---------------- l2_fused: tile 64 rows x 128 cols, K=512, 8 waves ----------------
    f16 (*As)[64][72] = (f16(*)[64][72])smem;              // 18432 B, reg-built, padded
    f16 (*Bs)[128*64] = (f16(*)[128*64])(smem + 18432);    // 32768 B, gload dest, swizzled
    const int lbid = bid - MG_L2;
    const bool hero = lbid < 192;
    const int row0 = hero ? lbid * 64 : (lbid - 192) * 64;
    const f16* Bt = hero ? hW2t : bW2t;
    const float* bias = hero ? hb2 : bb2;
    const int lane = tid & 63, wave = tid >> 6;
    const int lr = lane & 15;
    const int rw = wave & 3, cw = wave >> 2;   // wave = 16 rows x 64 cols

    // A-build: thread builds row br, 8-col chunk c8
    const int br = tid >> 3, c8 = (tid & 7) * 8;
    const int grow = row0 + br;
    const f16 *t0, *t1, *t2;
    if (hero) {
        const int HP0[6] = {0,0,0,1,1,2}, HP1[6] = {1,2,3,2,3,3};
        int m = grow / 6, p = grow - m * 6;
        t0 = T + (size_t)(0*53 + cid[m*9 + HP0[p]]) * 512;
        t1 = T + (size_t)(1*53 + cid[m*9 + HP1[p]]) * 512;
        t2 = T;   // slot0 card0 == all zeros
    } else {
        const int BT0[10] = {4,4,4,4,4,4,5,5,5,6};
        const int BT1[10] = {5,5,5,6,6,7,6,6,7,7};
        const int BT2[10] = {6,7,8,7,8,8,7,8,8,8};
        int m = grow / 10, t = grow - m * 10;
        t0 = T + (size_t)(2*53 + cid[m*9 + BT0[t]]) * 512;
        t1 = T + (size_t)(3*53 + cid[m*9 + BT1[t]]) * 512;
        t2 = T + (size_t)(4*53 + cid[m*9 + BT2[t]]) * 512;
    }

    auto stageB = [&](int buf, int k0) {
        #pragma unroll
        for (int i = 0; i < 2; ++i) {
            int c = tid + i * 512;                 // 1024 chunks: 128 rows x 8
            int r = c >> 3, cc = c & 7;
            gload16(Bt + (size_t)r * 512 + k0 + ((cc ^ (r & 7)) << 3), (void*)&Bs[buf][c * 8]);
        }
    };
    auto buildA = [&](int buf, int k0) {
        f16x8 a = *(const f16x8*)(t0 + k0 + c8);
        f16x8 b = *(const f16x8*)(t1 + k0 + c8);
        f16x8 c = *(const f16x8*)(t2 + k0 + c8);
        *(f16x8*)&As[buf][br][c8] = lrelu8(a + b + c);
    };

    f32x4 acc[4] = {};
    stageB(0, 0); buildA(0, 0);
    __syncthreads();
    for (int t = 0; t < 8; ++t) {
        int cur = t & 1;
        if (t < 7) { stageB(cur ^ 1, (t + 1) * 64); buildA(cur ^ 1, (t + 1) * 64); }
        #pragma unroll
        for (int kk2 = 0; kk2 < 2; ++kk2) {
            int g  = kk2 * 4 + (lane >> 4);
            int eo = (g ^ (lr & 7)) << 3;
            f16x8 a = *(const f16x8*)&As[cur][rw*16 + lr][kk2*32 + (lane >> 4)*8];
            #pragma unroll
            for (int j = 0; j < 4; ++j) {
                f16x8 b = *(const f16x8*)&Bs[cur][(cw*64 + j*16 + lr)*64 + eo];
                acc[j] = __builtin_amdgcn_mfma_f32_16x16x32_f16(a, b, acc[j], 0, 0, 0);
            }
        }
        __syncthreads();
    }
    #pragma unroll
    for (int j = 0; j < 4; ++j)
    #pragma unroll
    for (int q = 0; q < 4; ++q) {
        int row = row0 + rw*16 + (lane >> 4)*4 + q;
        int col = cw*64 + j*16 + lr;
        float v = lrelu(acc[j][q] + bias[col]);
        size_t off;
        if (hero) { int m = row / 6,  p = row - m*6;  off = (size_t)m*2048 + p*128 + col; }
        else      { int m = row / 10, p = row - m*10; off = (size_t)m*2048 + 768 + p*128 + col; }
        X[off] = (f16)v;
    }
}

// ===== generic f16 MFMA GEMM: C = lrelu(A @ Bt^T + bias). 64 x BN tile, 8 waves =====
template<int BN>
__global__ __launch_bounds__(512) void gemm_f16(const f16* __restrict__ A,
                                                const f16* __restrict__ Bt,
                                                const float* __restrict__ bias,
                                                f16* __restrict__ C,
                                                int K_, int ldc) {
    __shared__ __align__(16) f16 As[2][64 * 64];
    __shared__ __align__(16) f16 Bs[2][BN * 64];
    const int row0 = blockIdx.x * 64, col0 = blockIdx.y * BN;
    const int tid = threadIdx.x, lane = tid & 63, wave = tid >> 6;
    const int rw = wave >> 1, cw = wave & 1;       // wave = 16 rows x BN/2 cols
    const int lr = lane & 15;
    constexpr int NF = BN / 32;                    // 16-col frags per wave

    auto stage = [&](int buf, int k0) {
        { int c = tid; int r = c >> 3, cc = c & 7;   // As: 512 chunks
          gload16(A + (size_t)(row0 + r) * K_ + k0 + ((cc ^ (r & 7)) << 3), (void*)&As[buf][c * 8]); }
        for (int c = tid; c < BN * 8; c += 512) {    // Bs: BN*8 chunks
          int r = c >> 3, cc = c & 7;
          gload16(Bt + (size_t)(col0 + r) * K_ + k0 + ((cc ^ (r & 7)) << 3), (void*)&Bs[buf][c * 8]); }
    };

    f32x4 acc[NF] = {};
    stage(0, 0);
    __syncthreads();
    const int nt = K_ >> 6;
    for (int t = 0; t < nt; ++t) {
        int cur = t & 1;
        if (t + 1 < nt) stage(cur ^ 1, (t + 1) * 64);
        #pragma unroll
        for (int kk2 = 0; kk2 < 2; ++kk2) {
            int g  = kk2 * 4 + (lane >> 4);
            int eo = (g ^ (lr & 7)) << 3;
            f16x8 a = *(const f16x8*)&As[cur][(rw*16 + lr)*64 + eo];
            #pragma unroll
            for (int j = 0; j < NF; ++j) {
                f16x8 b = *(const f16x8*)&Bs[cur][(cw*(BN/2) + j*16 + lr)*64 + eo];
                acc[j] = __builtin_amdgcn_mfma_f32_16x16x32_f16(a, b, acc[j], 0, 0, 0);
            }
        }
        __syncthreads();
    }
    #pragma unroll
    for (int j = 0; j < NF; ++j)
    #pragma unroll
    for (int q = 0; q < 4; ++q) {
        int row = row0 + rw*16 + (lane >> 4)*4 + q;
        int col = col0 + cw*(BN/2) + j*16 + lr;
        C[(size_t)row * ldc + col] = (f16)lrelu(acc[j][q] + bias[col]);
    }
}

// ===== tail: R3 = lrelu(R2 @ oW3t^T + ob3) in LDS ; out = R3 @ sW + sb =====
// 128 blocks x 16 rows, 256 threads (4 waves), K=256 staged once.
__global__ __launch_bounds__(256) void tail_kernel(const f16* __restrict__ R2,
                                                   const f16* __restrict__ oW3t,
                                                   const float* __restrict__ ob3,
                                                   const float* __restrict__ sW,
                                                   const float* __restrict__ sb,
                                                   float* __restrict__ out) {
    __shared__ __align__(16) f16 As[16 * 256];     // 8KB
    __shared__ __align__(16) f16 Bs[128 * 256];    // 64KB
    __shared__ float R3s[16][132];
    __shared__ float sWs[127 * 9];
    __shared__ float sbs[9];
    const int row0 = blockIdx.x * 16;
    const int tid = threadIdx.x, lane = tid & 63, wave = tid >> 6;
    const int lr = lane & 15;

    for (int c = tid; c < 512; c += 256) {         // As: 16 rows x 32 chunks
        int r = c >> 5, cc = c & 31;
        gload16(R2 + (size_t)(row0 + r) * 256 + ((cc ^ (r & 7)) << 3), (void*)&As[c * 8]);
    }
    for (int c = tid; c < 4096; c += 256) {        // Bs: 128 rows x 32 chunks
        int r = c >> 5, cc = c & 31;
        gload16(oW3t + (size_t)r * 256 + ((cc ^ (r & 7)) << 3), (void*)&Bs[c * 8]);
    }
    for (int i = tid; i < 127 * 9; i += 256) sWs[i] = sW[i];
    if (tid < 9) sbs[tid] = sb[tid];
    __syncthreads();

    f32x4 acc[2] = {};
    #pragma unroll
    for (int kk2 = 0; kk2 < 8; ++kk2) {
        int g  = kk2 * 4 + (lane >> 4);
        int eo = (g ^ (lr & 7)) << 3;
        f16x8 a = *(const f16x8*)&As[lr * 256 + eo];
        #pragma unroll
        for (int j = 0; j < 2; ++j) {
            f16x8 b = *(const f16x8*)&Bs[(wave*32 + j*16 + lr) * 256 + eo];
            acc[j] = __builtin_amdgcn_mfma_f32_16x16x32_f16(a, b, acc[j], 0, 0, 0);
        }
    }
    #pragma unroll
    for (int j = 0; j < 2; ++j)
    #pragma unroll
    for (int q = 0; q < 4; ++q) {
        int row = (lane >> 4)*4 + q;
        int col = wave*32 + j*16 + lr;
        float b = (col < 127) ? ob3[col] : 0.f;
        R3s[row][col] = lrelu(acc[j][q] + b);
    }
    __syncthreads();
    if (tid < 16 * 9) {
        int row = tid / 9, a = tid - row * 9;
        float s = sbs[a];
        #pragma unroll 4
        for (int n = 0; n < 127; ++n) s += R3s[row][n] * sWs[n * 9 + a];
        out[(size_t)(row0 + row) * 9 + a] = s;
    }
}

extern "C" void kernel_launch(void* const* d_in, const int* in_sizes, int n_in,
                              void* d_out, int out_size, void* d_ws, size_t ws_size,
                              hipStream_t stream) {
    const int*   x    = (const int*)  d_in[0];
    const float* emb  = (const float*)d_in[1];
    const float* hW1  = (const float*)d_in[2];
    const float* hb1  = (const float*)d_in[3];
    const float* hW2  = (const float*)d_in[4];
    const float* hb2  = (const float*)d_in[5];
    const float* bW1  = (const float*)d_in[6];
    const float* bb1  = (const float*)d_in[7];
    const float* bW2  = (const float*)d_in[8];
    const float* bb2  = (const float*)d_in[9];
    const float* oW1  = (const float*)d_in[10];
    const float* ob1  = (const float*)d_in[11];
    const float* oW2  = (const float*)d_in[12];
    const float* ob2  = (const float*)d_in[13];
    const float* oW3  = (const float*)d_in[14];
    const float* ob3  = (const float*)d_in[15];
    const float* sW   = (const float*)d_in[16];
    const float* sb   = (const float*)d_in[17];

    char* ws = (char*)d_ws;
    constexpr size_t OFF_T    = 0;                     // 5*53*512 f16  = 271,360
    constexpr size_t OFF_HW2T = 271360;                // 128x512 f16   = 131,072
    constexpr size_t OFF_BW2T = OFF_HW2T + 131072;     // 402,432
    constexpr size_t OFF_OW2T = OFF_BW2T + 131072;     // 256x512 f16   = 262,144
    constexpr size_t OFF_OW3T = OFF_OW2T + 262144;     // 128x256 f16   = 65,536
    constexpr size_t OFF_WCT  = OFF_OW3T + 65536;      // 512x2048 f16  = 2,097,152
    constexpr size_t OFF_CID  = OFF_WCT + 2097152;     // 2048x9 i32    = 73,728
    constexpr size_t OFF_X    = OFF_CID + 73728;       // 2048x2048 f16 = 8,388,608
    constexpr size_t OFF_R1   = OFF_X + 8388608;       // 2048x512 f16  = 2,097,152
    constexpr size_t OFF_R2   = OFF_R1 + 2097152;      // 2048x256 f16  = 1,048,576

    f16*  T    = (f16*)(ws + OFF_T);
    f16*  hW2t = (f16*)(ws + OFF_HW2T);
    f16*  bW2t = (f16*)(ws + OFF_BW2T);
    f16*  oW2t = (f16*)(ws + OFF_OW2T);
    f16*  oW3t = (f16*)(ws + OFF_OW3T);
    f16*  Wct  = (f16*)(ws + OFF_WCT);
    int*  cid  = (int*)(ws + OFF_CID);
    f16*  X    = (f16*)(ws + OFF_X);
    f16*  R1   = (f16*)(ws + OFF_R1);
    f16*  R2   = (f16*)(ws + OFF_R2);

    prep1<<<P1_END, 512, 0, stream>>>(x, emb, hW1, hb1, hW2, bW1, bb1, bW2,
                                      oW2, oW3, T, hW2t, bW2t, oW2t, oW3t, cid);
    mega<<<MG_END, 512, 0, stream>>>(cid, T, hW2t, bW2t, hb2, bb2, oW1, X, Wct);
    gemm_f16<64><<<dim3(32, 8), 512, 0, stream>>>(X,  Wct,  ob1, R1, 2048, 512);
    gemm_f16<32><<<dim3(32, 8), 512, 0, stream>>>(R1, oW2t, ob2, R2, 512, 256);
    tail_kernel<<<128, 256, 0, stream>>>(R2, oW3t, ob3, sW, sb, (float*)d_out);
}

// Round 7
// 56.210 us; speedup vs baseline: 3.3624x; 1.0769x over previous
//
#include <hip/hip_runtime.h>

typedef _Float16 f16;
typedef __attribute__((ext_vector_type(8))) _Float16 f16x8;
typedef __attribute__((ext_vector_type(4))) _Float16 f16x4;
typedef __attribute__((ext_vector_type(4))) float f32x4;

__device__ inline float lrelu(float v){ return v > 0.f ? v : 0.01f*v; }
__device__ inline f16x8 lrelu8(f16x8 v){
    f16x8 z = {};
    f16x8 mx = __builtin_elementwise_max(v, z);
    f16x8 mn = __builtin_elementwise_min(v, z);
    return mx + mn * (f16)0.01f;
}

__device__ __forceinline__ void gload16(const void* gp, void* lp) {
    __builtin_amdgcn_global_load_lds(
        (const __attribute__((address_space(1))) unsigned int*)gp,
        (__attribute__((address_space(3))) unsigned int*)lp,
        16, 0, 0);
}

#define M_ROWS 2048

// ======================= launch 1: prep needed by l2_fused =======================
//   [0,265)    prep_T : T[slot][card][512] = emb[card] @ Wslice (+bias folded), f16
//   [265,393)  hW2t   : transpose->f16 128x512
//   [393,521)  bW2t   : transpose->f16 128x512
//   [521,525)  cards  : parse+sort -> cid
#define P1_T    0
#define P1_HW2  265
#define P1_BW2  393
#define P1_CARD 521
#define P1_END  525

__device__ void d_transpose512(const float* __restrict__ in, f16* __restrict__ out,
                               int K, int Nin, int Nout, int b, int tid) {
    int idx = b * 512 + tid;
    if (idx >= Nout * K) return;
    int n = idx / K, k = idx - n * K;
    float v = (n < Nin) ? in[(size_t)k * Nin + n] : 0.f;
    out[idx] = (f16)v;
}

__global__ __launch_bounds__(512) void prep1(const int* __restrict__ x,
                                             const float* __restrict__ emb,
                                             const float* __restrict__ hW1,
                                             const float* __restrict__ hb1,
                                             const float* __restrict__ hW2,
                                             const float* __restrict__ bW1,
                                             const float* __restrict__ bb1,
                                             const float* __restrict__ bW2,
                                             f16* __restrict__ T,
                                             f16* __restrict__ hW2t,
                                             f16* __restrict__ bW2t,
                                             int* __restrict__ cid) {
    const int bid = blockIdx.x, tid = threadIdx.x;
    if (bid < P1_HW2) {
        int b = bid;                 // slot*53 + card
        int slot = b / 53, card = b - slot * 53;
        const float* W = (slot < 2) ? (hW1 + slot * 64 * 512) : (bW1 + (slot - 2) * 64 * 512);
        const float* e = emb + card * 64;
        float acc = (slot == 1) ? hb1[tid] : ((slot == 4) ? bb1[tid] : 0.f);
        #pragma unroll 8
        for (int k = 0; k < 64; ++k) acc += e[k] * W[k * 512 + tid];
        T[(size_t)b * 512 + tid] = (f16)acc;
    } else if (bid < P1_BW2) {
        d_transpose512(hW2, hW2t, 512, 128, 128, bid - P1_HW2, tid);
    } else if (bid < P1_CARD) {
        d_transpose512(bW2, bW2t, 512, 128, 128, bid - P1_BW2, tid);
    } else {
        int m = (bid - P1_CARD) * 512 + tid;
        if (m >= M_ROWS) return;
        int kh[4], kb[5];
        #pragma unroll
        for (int i = 0; i < 4; ++i) { int r = x[m*18 + 2*i], s = x[m*18 + 2*i + 1]; kh[i] = r*8 + s; }
        #pragma unroll
        for (int i = 0; i < 5; ++i) { int r = x[m*18 + 8 + 2*i], s = x[m*18 + 9 + 2*i]; kb[i] = r*8 + s; }
        #pragma unroll
        for (int i = 1; i < 4; ++i) { int v = kh[i], j = i-1; while (j >= 0 && kh[j] > v) { kh[j+1]=kh[j]; --j; } kh[j+1]=v; }
        #pragma unroll
        for (int i = 1; i < 5; ++i) { int v = kb[i], j = i-1; while (j >= 0 && kb[j] > v) { kb[j+1]=kb[j]; --j; } kb[j+1]=v; }
        #pragma unroll
        for (int i = 0; i < 4; ++i) { int r = kh[i] >> 3, s = kh[i] & 7; cid[m*9 + i] = (r - 1) * s; }
        #pragma unroll
        for (int i = 0; i < 5; ++i) { int r = kb[i] >> 3, s = kb[i] & 7; cid[m*9 + 4 + i] = (r - 1) * s; }
    }
}

// ===== launch 2 (mega): Wct (first: starts HBM stream) + l2_fused + oW2t/oW3t =====
//   [0,256)      prep_Wct : Wct[512][2048] f16 block-sum-transpose of oW1
//   [256,768)    l2_fused : fused layer-1 build + layer-2 GEMM -> X (f16)
//   [768,1024)   oW2t     : transpose->f16 256x512
//   [1024,1088)  oW3t     : transpose->f16 128x256 (row 127 zero-pad)
#define MG_L2   256
#define MG_OW2  768
#define MG_OW3  1024
#define MG_END  1088

__global__ __launch_bounds__(512, 4) void mega(const int* __restrict__ cid,
                                               const f16* __restrict__ T,
                                               const f16* __restrict__ hW2t,
                                               const f16* __restrict__ bW2t,
                                               const float* __restrict__ hb2,
                                               const float* __restrict__ bb2,
                                               const float* __restrict__ oW1,
                                               const float* __restrict__ oW2,
                                               const float* __restrict__ oW3,
                                               f16* __restrict__ X,
                                               f16* __restrict__ Wct,
                                               f16* __restrict__ oW2t,
                                               f16* __restrict__ oW3t) {
    __shared__ __align__(16) char smem[51200];
    const int bid = blockIdx.x, tid = threadIdx.x;

    if (bid < MG_L2) {
        // ---------------- prep_Wct ----------------
        float (*tile)[65] = (float(*)[65])smem;
        int kb = bid & 31, nb = bid >> 5;
        int nl = tid & 63;
        for (int kl = tid >> 6; kl < 64; kl += 8) {
            int col = kb * 64 + kl;
            int p = col >> 7, r = col & 127;
            int n = nb * 64 + nl;
            float s = 0.f;
            if (p < 6) {
                #pragma unroll
                for (int j = 0; j < 10; ++j) s += oW1[(size_t)((p * 10 + j) * 256 + r) * 512 + n];
            } else {
                int t = p - 6;
                #pragma unroll
                for (int i = 0; i < 6; ++i) s += oW1[(size_t)((i * 10 + t) * 256 + 128 + r) * 512 + n];
            }
            tile[kl][nl] = s;
        }
        __syncthreads();
        for (int nl2 = tid >> 6; nl2 < 64; nl2 += 8) {
            int kl2 = tid & 63;
            Wct[(size_t)(nb * 64 + nl2) * 2048 + kb * 64 + kl2] = (f16)tile[kl2][nl2];
        }
        return;
    }
    if (bid >= MG_OW3) {
        d_transpose512(oW3, oW3t, 256, 127, 128, bid - MG_OW3, tid);
        return;
    }
    if (bid >= MG_OW2) {
        d_transpose512(oW2, oW2t, 512, 256, 256, bid - MG_OW2, tid);
        return;
    }

    // ---------------- l2_fused: tile 64 rows x 128 cols, K=512, 8 waves ----------------
    f16 (*As)[64][72] = (f16(*)[64][72])smem;              // 18432 B, reg-built, padded
    f16 (*Bs)[128*64] = (f16(*)[128*64])(smem + 18432);    // 32768 B, gload dest, swizzled
    const int lbid = bid - MG_L2;
    const bool hero = lbid < 192;
    const int row0 = hero ? lbid * 64 : (lbid - 192) * 64;
    const f16* Bt = hero ? hW2t : bW2t;
    const float* bias = hero ? hb2 : bb2;
    const int lane = tid & 63, wave = tid >> 6;
    const int lr = lane & 15;
    const int rw = wave & 3, cw = wave >> 2;   // wave = 16 rows x 64 cols

    const int br = tid >> 3, c8 = (tid & 7) * 8;
    const int grow = row0 + br;
    const f16 *t0, *t1, *t2;
    if (hero) {
        const int HP0[6] = {0,0,0,1,1,2}, HP1[6] = {1,2,3,2,3,3};
        int m = grow / 6, p = grow - m * 6;
        t0 = T + (size_t)(0*53 + cid[m*9 + HP0[p]]) * 512;
        t1 = T + (size_t)(1*53 + cid[m*9 + HP1[p]]) * 512;
        t2 = T;   // slot0 card0 == all zeros
    } else {
        const int BT0[10] = {4,4,4,4,4,4,5,5,5,6};
        const int BT1[10] = {5,5,5,6,6,7,6,6,7,7};
        const int BT2[10] = {6,7,8,7,8,8,7,8,8,8};
        int m = grow / 10, t = grow - m * 10;
        t0 = T + (size_t)(2*53 + cid[m*9 + BT0[t]]) * 512;
        t1 = T + (size_t)(3*53 + cid[m*9 + BT1[t]]) * 512;
        t2 = T + (size_t)(4*53 + cid[m*9 + BT2[t]]) * 512;
    }

    auto stageB = [&](int buf, int k0) {
        #pragma unroll
        for (int i = 0; i < 2; ++i) {
            int c = tid + i * 512;                 // 1024 chunks: 128 rows x 8
            int r = c >> 3, cc = c & 7;
            gload16(Bt + (size_t)r * 512 + k0 + ((cc ^ (r & 7)) << 3), (void*)&Bs[buf][c * 8]);
        }
    };
    auto buildA = [&](int buf, int k0) {
        f16x8 a = *(const f16x8*)(t0 + k0 + c8);
        f16x8 b = *(const f16x8*)(t1 + k0 + c8);
        f16x8 c = *(const f16x8*)(t2 + k0 + c8);
        *(f16x8*)&As[buf][br][c8] = lrelu8(a + b + c);
    };

    f32x4 acc[4] = {};
    stageB(0, 0); buildA(0, 0);
    __syncthreads();
    for (int t = 0; t < 8; ++t) {
        int cur = t & 1;
        if (t < 7) { stageB(cur ^ 1, (t + 1) * 64); buildA(cur ^ 1, (t + 1) * 64); }
        #pragma unroll
        for (int kk2 = 0; kk2 < 2; ++kk2) {
            int g  = kk2 * 4 + (lane >> 4);
            int eo = (g ^ (lr & 7)) << 3;
            f16x8 a = *(const f16x8*)&As[cur][rw*16 + lr][kk2*32 + (lane >> 4)*8];
            #pragma unroll
            for (int j = 0; j < 4; ++j) {
                f16x8 b = *(const f16x8*)&Bs[cur][(cw*64 + j*16 + lr)*64 + eo];
                acc[j] = __builtin_amdgcn_mfma_f32_16x16x32_f16(a, b, acc[j], 0, 0, 0);
            }
        }
        __syncthreads();
    }
    #pragma unroll
    for (int j = 0; j < 4; ++j)
    #pragma unroll
    for (int q = 0; q < 4; ++q) {
        int row = row0 + rw*16 + (lane >> 4)*4 + q;
        int col = cw*64 + j*16 + lr;
        float v = lrelu(acc[j][q] + bias[col]);
        size_t off;
        if (hero) { int m = row / 6,  p = row - m*6;  off = (size_t)m*2048 + p*128 + col; }
        else      { int m = row / 10, p = row - m*10; off = (size_t)m*2048 + 768 + p*128 + col; }
        X[off] = (f16)v;
    }
}

// ===== launch 3: combine, split-K=2, BN=128, XCD-swizzled. R1p = X @ Wct^T (f32 raw) =====
__global__ __launch_bounds__(512, 4) void combine(const f16* __restrict__ X,
                                                  const f16* __restrict__ Wct,
                                                  float* __restrict__ R1p) {
    __shared__ __align__(16) f16 As[2][64 * 64];    // 16KB
    __shared__ __align__(16) f16 Bs[2][128 * 64];   // 32KB
    // bijective decode: all blocks sharing a row panel land on the same XCD
    const int bid = blockIdx.x;                     // 0..255
    const int xcd = bid & 7, slot = bid >> 3;       // slot 0..31
    const int rp = xcd * 4 + (slot & 3);            // row panel 0..31
    const int rest = slot >> 2;                     // 0..7
    const int cp = rest & 3, ks = rest >> 2;        // col panel 0..3, k-split 0..1
    const int row0 = rp * 64, col0 = cp * 128, k0b = ks * 1024;
    const int tid = threadIdx.x, lane = tid & 63, wave = tid >> 6;
    const int rw = wave & 3, cw = wave >> 2;        // wave = 16 rows x 64 cols
    const int lr = lane & 15;

    auto stage = [&](int buf, int k0) {
        { int r = tid >> 3, cc = tid & 7;
          gload16(X + (size_t)(row0 + r) * 2048 + k0 + ((cc ^ (r & 7)) << 3), (void*)&As[buf][tid * 8]); }
        #pragma unroll
        for (int i = 0; i < 2; ++i) {
            int c = tid + i * 512;
            int r = c >> 3, cc = c & 7;
            gload16(Wct + (size_t)(col0 + r) * 2048 + k0 + ((cc ^ (r & 7)) << 3), (void*)&Bs[buf][c * 8]);
        }
    };

    f32x4 acc[4] = {};
    stage(0, k0b);
    __syncthreads();
    for (int t = 0; t < 16; ++t) {
        int cur = t & 1;
        if (t < 15) stage(cur ^ 1, k0b + (t + 1) * 64);
        #pragma unroll
        for (int kk2 = 0; kk2 < 2; ++kk2) {
            int g  = kk2 * 4 + (lane >> 4);
            int eo = (g ^ (lr & 7)) << 3;
            f16x8 a = *(const f16x8*)&As[cur][(rw * 16 + lr) * 64 + eo];
            #pragma unroll
            for (int j = 0; j < 4; ++j) {
                f16x8 b = *(const f16x8*)&Bs[cur][(cw * 64 + j * 16 + lr) * 64 + eo];
                acc[j] = __builtin_amdgcn_mfma_f32_16x16x32_f16(a, b, acc[j], 0, 0, 0);
            }
        }
        __syncthreads();
    }
    float* dst = R1p + (size_t)ks * 2048 * 512;
    #pragma unroll
    for (int j = 0; j < 4; ++j)
    #pragma unroll
    for (int q = 0; q < 4; ++q) {
        int row = row0 + rw * 16 + (lane >> 4) * 4 + q;
        int col = col0 + cw * 64 + j * 16 + lr;
        dst[(size_t)row * 512 + col] = acc[j][q];
    }
}

// ===== launch 4: tail2 = add K-halves + ob1 + lrelu -> R2 GEMM -> R3 GEMM -> out =====
// 128 blocks x 16 rows, 512 threads.
__global__ __launch_bounds__(512, 2) void tail2(const float* __restrict__ R1p,
                                                const float* __restrict__ ob1,
                                                const f16* __restrict__ oW2t,
                                                const float* __restrict__ ob2,
                                                const f16* __restrict__ oW3t,
                                                const float* __restrict__ ob3,
                                                const float* __restrict__ sW,
                                                const float* __restrict__ sb,
                                                float* __restrict__ out) {
    __shared__ __align__(16) f16 A1s[16 * 512];     // 16KB (swizzled)
    __shared__ __align__(16) f16 Bs[2][256 * 64];   // 64KB
    __shared__ __align__(16) f16 R2s[16 * 256];     // 8KB (swizzled)
    __shared__ float R3s[16][132];
    __shared__ float sWs[127 * 9];
    __shared__ float sbs[9];
    const int row0 = blockIdx.x * 16;
    const int tid = threadIdx.x, lane = tid & 63, wave = tid >> 6;
    const int lr = lane & 15;

    auto stageB2 = [&](int buf, int t) {            // oW2t: 256 rows x 8 chunks = 2048
        #pragma unroll
        for (int i = 0; i < 4; ++i) {
            int c = tid + i * 512;
            int r = c >> 3, cc = c & 7;
            gload16(oW2t + (size_t)r * 512 + t * 64 + ((cc ^ (r & 7)) << 3), (void*)&Bs[buf][c * 8]);
        }
    };
    stageB2(0, 0);                                  // overlap with phase A

    // --- phase A: A1 = lrelu(R1p[0] + R1p[1] + ob1) -> swizzled f16 A1s ---
    #pragma unroll
    for (int i = 0; i < 4; ++i) {
        int g = tid + i * 512;                      // 2048 f32x4 groups
        int row = g >> 7, c4 = (g & 127) << 2;
        f32x4 a = *(const f32x4*)(R1p + (size_t)(row0 + row) * 512 + c4);
        f32x4 b = *(const f32x4*)(R1p + (size_t)2048 * 512 + (size_t)(row0 + row) * 512 + c4);
        f32x4 o = *(const f32x4*)(ob1 + c4);
        f16x4 p;
        #pragma unroll
        for (int q = 0; q < 4; ++q) p[q] = (f16)lrelu(a[q] + b[q] + o[q]);
        int chunk = c4 >> 3, half = (c4 >> 2) & 1;
        *(f16x4*)&A1s[row * 512 + ((chunk ^ (row & 7)) << 3) + half * 4] = p;
    }
    for (int i = tid; i < 127 * 9; i += 512) sWs[i] = sW[i];
    if (tid < 9) sbs[tid] = sb[tid];
    __syncthreads();

    // --- phase B: R2 = lrelu(A1 @ oW2t^T + ob2), 16x256, K=512, 8 steps ---
    f32x4 acc2[2] = {};
    for (int t = 0; t < 8; ++t) {
        int cur = t & 1;
        if (t < 7) stageB2(cur ^ 1, t + 1);
        #pragma unroll
        for (int kk2 = 0; kk2 < 2; ++kk2) {
            int g  = kk2 * 4 + (lane >> 4);
            int gg = t * 8 + g;
            f16x8 a = *(const f16x8*)&A1s[lr * 512 + ((gg ^ (lr & 7)) << 3)];
            int eo = (g ^ (lr & 7)) << 3;
            #pragma unroll
            for (int j = 0; j < 2; ++j) {
                f16x8 b = *(const f16x8*)&Bs[cur][(wave * 32 + j * 16 + lr) * 64 + eo];
                acc2[j] = __builtin_amdgcn_mfma_f32_16x16x32_f16(a, b, acc2[j], 0, 0, 0);
            }
        }
        __syncthreads();
    }
    #pragma unroll
    for (int j = 0; j < 2; ++j)
    #pragma unroll
    for (int q = 0; q < 4; ++q) {
        int row = (lane >> 4) * 4 + q;
        int col = wave * 32 + j * 16 + lr;
        f16 v = (f16)lrelu(acc2[j][q] + ob2[col]);
        int chunk = col >> 3, w = col & 7;
        R2s[row * 256 + ((chunk ^ (row & 7)) << 3) + w] = v;
    }
    auto stageB3 = [&](int buf, int t) {            // oW3t: 128 rows x 8 chunks = 1024
        #pragma unroll
        for (int i = 0; i < 2; ++i) {
            int c = tid + i * 512;
            if (c < 1024) {
                int r = c >> 3, cc = c & 7;
                gload16(oW3t + (size_t)r * 256 + t * 64 + ((cc ^ (r & 7)) << 3), (void*)&Bs[buf][c * 8]);
            }
        }
    };
    stageB3(0, 0);
    __syncthreads();

    // --- phase C: R3 = lrelu(R2 @ oW3t^T + ob3), 16x128, K=256, 4 steps ---
    f32x4 acc3 = {};
    for (int t = 0; t < 4; ++t) {
        int cur = t & 1;
        if (t < 3) stageB3(cur ^ 1, t + 1);
        #pragma unroll
        for (int kk2 = 0; kk2 < 2; ++kk2) {
            int g  = kk2 * 4 + (lane >> 4);
            int gg = t * 8 + g;
            f16x8 a = *(const f16x8*)&R2s[lr * 256 + ((gg ^ (lr & 7)) << 3)];
            int eo = (g ^ (lr & 7)) << 3;
            f16x8 b = *(const f16x8*)&Bs[cur][(wave * 16 + lr) * 64 + eo];
            acc3 = __builtin_amdgcn_mfma_f32_16x16x32_f16(a, b, acc3, 0, 0, 0);
        }
        __syncthreads();
    }
    #pragma unroll
    for (int q = 0; q < 4; ++q) {
        int row = (lane >> 4) * 4 + q;
        int col = wave * 16 + lr;
        R3s[row][col] = lrelu(acc3[q] + ((col < 127) ? ob3[col] : 0.f));
    }
    __syncthreads();

    // --- phase D: out = R3 @ sW + sb ---
    if (tid < 16 * 9) {
        int row = tid / 9, a = tid - row * 9;
        float s = sbs[a];
        #pragma unroll 4
        for (int n = 0; n < 127; ++n) s += R3s[row][n] * sWs[n * 9 + a];
        out[(size_t)(row0 + row) * 9 + a] = s;
    }
}

extern "C" void kernel_launch(void* const* d_in, const int* in_sizes, int n_in,
                              void* d_out, int out_size, void* d_ws, size_t ws_size,
                              hipStream_t stream) {
    const int*   x    = (const int*)  d_in[0];
    const float* emb  = (const float*)d_in[1];
    const float* hW1  = (const float*)d_in[2];
    const float* hb1  = (const float*)d_in[3];
    const float* hW2  = (const float*)d_in[4];
    const float* hb2  = (const float*)d_in[5];
    const float* bW1  = (const float*)d_in[6];
    const float* bb1  = (const float*)d_in[7];
    const float* bW2  = (const float*)d_in[8];
    const float* bb2  = (const float*)d_in[9];
    const float* oW1  = (const float*)d_in[10];
    const float* ob1  = (const float*)d_in[11];
    const float* oW2  = (const float*)d_in[12];
    const float* ob2  = (const float*)d_in[13];
    const float* oW3  = (const float*)d_in[14];
    const float* ob3  = (const float*)d_in[15];
    const float* sW   = (const float*)d_in[16];
    const float* sb   = (const float*)d_in[17];

    char* ws = (char*)d_ws;
    constexpr size_t OFF_T    = 0;                     // 5*53*512 f16   = 271,360
    constexpr size_t OFF_HW2T = 271360;                // 128x512 f16    = 131,072
    constexpr size_t OFF_BW2T = OFF_HW2T + 131072;     // 402,432
    constexpr size_t OFF_OW2T = OFF_BW2T + 131072;     // 256x512 f16    = 262,144
    constexpr size_t OFF_OW3T = OFF_OW2T + 262144;     // 128x256 f16    = 65,536
    constexpr size_t OFF_WCT  = OFF_OW3T + 65536;      // 512x2048 f16   = 2,097,152
    constexpr size_t OFF_CID  = OFF_WCT + 2097152;     // 2048x9 i32     = 73,728
    constexpr size_t OFF_X    = OFF_CID + 73728;       // 2048x2048 f16  = 8,388,608
    constexpr size_t OFF_R1P  = OFF_X + 8388608;       // 2x2048x512 f32 = 8,388,608

    f16*   T    = (f16*)(ws + OFF_T);
    f16*   hW2t = (f16*)(ws + OFF_HW2T);
    f16*   bW2t = (f16*)(ws + OFF_BW2T);
    f16*   oW2t = (f16*)(ws + OFF_OW2T);
    f16*   oW3t = (f16*)(ws + OFF_OW3T);
    f16*   Wct  = (f16*)(ws + OFF_WCT);
    int*   cid  = (int*)(ws + OFF_CID);
    f16*   X    = (f16*)(ws + OFF_X);
    float* R1p  = (float*)(ws + OFF_R1P);

    prep1<<<P1_END, 512, 0, stream>>>(x, emb, hW1, hb1, hW2, bW1, bb1, bW2,
                                      T, hW2t, bW2t, cid);
    mega<<<MG_END, 512, 0, stream>>>(cid, T, hW2t, bW2t, hb2, bb2,
                                     oW1, oW2, oW3, X, Wct, oW2t, oW3t);
    combine<<<256, 512, 0, stream>>>(X, Wct, R1p);
    tail2<<<128, 512, 0, stream>>>(R1p, ob1, oW2t, ob2, oW3t, ob3, sW, sb, (float*)d_out);
}